// Round 12
// baseline (1448.783 us; speedup 1.0000x reference)
//
#include <hip/hip_runtime.h>
#include <hip/hip_bf16.h>
#include <stdint.h>

typedef unsigned short u16;
typedef unsigned int   u32;
typedef __attribute__((ext_vector_type(8))) short v8s;
typedef __attribute__((ext_vector_type(4))) float v4f;

__device__ __forceinline__ float b2f(u16 u){ return __uint_as_float(((u32)u) << 16); }
__device__ __forceinline__ float lo2f(u32 u){ return __uint_as_float(u << 16); }
__device__ __forceinline__ float hi2f(u32 u){ return __uint_as_float(u & 0xffff0000u); }
__device__ __forceinline__ u16 f2b(float f){
    u32 x = __float_as_uint(f);
    u32 r = (x + 0x7fffu + ((x >> 16) & 1u)) >> 16;
    return (u16)r;
}
__device__ __forceinline__ float ldm(const void* p, size_t i, int isbf){
    return isbf ? b2f(((const u16*)p)[i]) : ((const float*)p)[i];
}
__device__ __forceinline__ float wred_sum(float v){
    #pragma unroll
    for (int o = 32; o > 0; o >>= 1) v += __shfl_xor(v, o, 64);
    return v;
}
__device__ __forceinline__ float wred_max(float v){
    #pragma unroll
    for (int o = 32; o > 0; o >>= 1) v = fmaxf(v, __shfl_xor(v, o, 64));
    return v;
}
__device__ __forceinline__ float wred16_sum(float v){
    #pragma unroll
    for (int o = 8; o > 0; o >>= 1) v += __shfl_xor(v, o, 64);
    return v;
}
__device__ __forceinline__ float wred16_max(float v){
    #pragma unroll
    for (int o = 8; o > 0; o >>= 1) v = fmaxf(v, __shfl_xor(v, o, 64));
    return v;
}
__device__ __forceinline__ float block_sum256(float v, float* red, int tid){
    float s = wred_sum(v);
    __syncthreads();
    if ((tid & 63) == 0) red[tid >> 6] = s;
    __syncthreads();
    return red[0] + red[1] + red[2] + red[3];
}
__device__ __forceinline__ void block_sum2(float& a, float& b, float (*red)[2], int tid){
    a = wred_sum(a); b = wred_sum(b);
    __syncthreads();
    if ((tid & 63) == 0){ red[tid >> 6][0] = a; red[tid >> 6][1] = b; }
    __syncthreads();
    a = red[0][0] + red[1][0] + red[2][0] + red[3][0];
    b = red[0][1] + red[1][1] + red[2][1] + red[3][1];
}
__device__ __forceinline__ void lds_fence(){
    asm volatile("s_waitcnt lgkmcnt(0)" ::: "memory");
    __builtin_amdgcn_sched_barrier(0);
}

__global__ void probe_kernel(const u32* __restrict__ ng, int* __restrict__ flag){
    if (threadIdx.x == 0) *flag = (ng[0] == 0x3F803F80u) ? 1 : 0;
}

#define NSEG 25
struct ConvArgs {
    const void* src[NSEG];
    u16*        dst[NSEG];
    int         n[NSEG];
};
__global__ __launch_bounds__(256) void convert_kernel(ConvArgs a, const int* __restrict__ flag){
    int seg = blockIdx.y;
    int i = blockIdx.x * 256 + threadIdx.x;
    if (i >= a.n[seg]) return;
    int isbf = *flag;
    a.dst[seg][i] = f2b(ldm(a.src[seg], i, isbf));
}
__global__ __launch_bounds__(256) void convert_time_kernel(const void* __restrict__ src,
                                                           float* __restrict__ dst,
                                                           const int* __restrict__ flag){
    int i = blockIdx.x * 256 + threadIdx.x;
    if (i >= 51200) return;
    dst[i] = ldm(src, i, *flag);
}

// pack [nlayer][K][N] bf16 weights into MFMA B-fragment order
__global__ __launch_bounds__(256) void packfrag_kernel(
    const u16* __restrict__ W, u16* __restrict__ out, int K, int N, int nlayer)
{
    int i = blockIdx.x * 256 + threadIdx.x;
    int total = nlayer * K * N;
    if (i >= total) return;
    int j = i & 7, lane = (i >> 3) & 63, fc = i >> 9;
    int CT = K >> 5, NT = N >> 4;
    int c = fc % CT, nt = (fc / CT) % NT, layer = fc / (CT * NT);
    int k = c * 32 + ((lane >> 4) << 3) + j, n = (nt << 4) + (lane & 15);
    out[i] = W[(layer * K + k) * N + n];
}

// pack QKV (3x [2][256][256]) into one fragment buffer as N=768
__global__ __launch_bounds__(256) void packfrag3_kernel(
    const u16* __restrict__ Wq, const u16* __restrict__ Wk, const u16* __restrict__ Wv,
    u16* __restrict__ out)
{
    int i = blockIdx.x * 256 + threadIdx.x;
    if (i >= 786432) return;
    int j = i & 7, lane = (i >> 3) & 63, fc = i >> 9;
    int c = fc & 7, nt = (fc >> 3) % 48, layer = fc / (8 * 48);
    int k = c * 32 + ((lane >> 4) << 3) + j, n = (nt << 4) + (lane & 15);
    const u16* W = (n < 256) ? Wq : (n < 512) ? Wk : Wv;
    out[i] = W[(layer * 256 + k) * 256 + (n & 255)];
}

// =======================================================================
// gemm2: LDS-free MFMA GEMM
// =======================================================================
template<int ACT, int SPLIT>
__global__ __launch_bounds__(256) void gemm2_kernel(
    const u16* __restrict__ A, const u16* __restrict__ Bf,
    const u16* __restrict__ bias,
    u16* __restrict__ C0, u16* __restrict__ C1, u16* __restrict__ C2,
    int M, int N, int K)
{
    const int tid = threadIdx.x, w = tid >> 6, lane = tid & 63;
    const int wm = w >> 1, wn = w & 1;
    const int m0 = blockIdx.x * 128 + wm * 64;
    const int n0 = blockIdx.y * 128 + wn * 64;
    const int CT = K >> 5;
    const int l15 = lane & 15, lg = lane >> 4;

    v4f acc[4][4];
    #pragma unroll
    for (int mt = 0; mt < 4; mt++)
        #pragma unroll
        for (int nt = 0; nt < 4; nt++) acc[mt][nt] = (v4f){0.f, 0.f, 0.f, 0.f};

    const u16* Arow = A + (size_t)(m0 + l15) * K + (lg << 3);
    const u16* Bbase = Bf + (((size_t)(n0 >> 4) * CT) << 9) + (lane << 3);

    for (int c = 0; c < CT; c++){
        v8s bfr[4];
        #pragma unroll
        for (int nt = 0; nt < 4; nt++)
            bfr[nt] = *(const v8s*)(Bbase + (((size_t)(nt * CT + c)) << 9));
        #pragma unroll
        for (int mt = 0; mt < 4; mt++){
            v8s af = *(const v8s*)(Arow + (size_t)(mt << 4) * K + (c << 5));
            #pragma unroll
            for (int nt = 0; nt < 4; nt++)
                acc[mt][nt] = __builtin_amdgcn_mfma_f32_16x16x32_bf16(af, bfr[nt], acc[mt][nt], 0, 0, 0);
        }
    }

    #pragma unroll
    for (int nt = 0; nt < 4; nt++){
        int colbase = n0 + (nt << 4);
        float bv = bias ? b2f(bias[colbase + l15]) : 0.f;
        u16* Cp; int cw;
        if (SPLIT){
            int nb = colbase >> 8;
            Cp = (nb == 0) ? C0 : (nb == 1) ? C1 : C2;
            cw = 256;
            colbase &= 255;
        } else { Cp = C0; cw = N; }
        #pragma unroll
        for (int mt = 0; mt < 4; mt++)
            #pragma unroll
            for (int r = 0; r < 4; r++){
                int row = m0 + (mt << 4) + (lg << 2) + r;
                float v = acc[mt][nt][r] + bv;
                if (ACT) v = fmaxf(v, 0.f);
                Cp[(size_t)row * cw + colbase + l15] = f2b(v);
            }
    }
}

// =======================================================================
// gemm3: FFN2 + residual + LN fused
// =======================================================================
__global__ __launch_bounds__(256) void gemm3_kernel(
    const u16* __restrict__ A, const u16* __restrict__ Bf,
    const u16* __restrict__ bias, u16* __restrict__ SRC,
    const u16* __restrict__ g, const u16* __restrict__ bta)
{
    __shared__ float red[64][4][2];
    const int tid = threadIdx.x, w = tid >> 6, lane = tid & 63;
    const int l15 = lane & 15, lg = lane >> 4;
    const int m0 = blockIdx.x * 64;
    const int n0 = w * 64;
    const int CT = 16;

    v4f acc[4][4];
    #pragma unroll
    for (int mt = 0; mt < 4; mt++)
        #pragma unroll
        for (int nt = 0; nt < 4; nt++) acc[mt][nt] = (v4f){0.f, 0.f, 0.f, 0.f};

    const u16* Arow = A + (size_t)(m0 + l15) * 512 + (lg << 3);
    const u16* Bbase = Bf + (((size_t)(n0 >> 4) * CT) << 9) + (lane << 3);

    for (int c = 0; c < CT; c++){
        v8s bfr[4];
        #pragma unroll
        for (int nt = 0; nt < 4; nt++)
            bfr[nt] = *(const v8s*)(Bbase + (((size_t)(nt * CT + c)) << 9));
        #pragma unroll
        for (int mt = 0; mt < 4; mt++){
            v8s af = *(const v8s*)(Arow + (size_t)(mt << 4) * 512 + (c << 5));
            #pragma unroll
            for (int nt = 0; nt < 4; nt++)
                acc[mt][nt] = __builtin_amdgcn_mfma_f32_16x16x32_bf16(af, bfr[nt], acc[mt][nt], 0, 0, 0);
        }
    }

    float bv[4];
    #pragma unroll
    for (int nt = 0; nt < 4; nt++) bv[nt] = b2f(bias[n0 + (nt << 4) + l15]);
    #pragma unroll
    for (int mt = 0; mt < 4; mt++){
        #pragma unroll
        for (int r = 0; r < 4; r++){
            int row = m0 + (mt << 4) + (lg << 2) + r;
            float s1 = 0.f, s2 = 0.f;
            #pragma unroll
            for (int nt = 0; nt < 4; nt++){
                int col = n0 + (nt << 4) + l15;
                float y = acc[mt][nt][r] + bv[nt] + b2f(SRC[(size_t)row * 256 + col]);
                acc[mt][nt][r] = y;
                s1 += y; s2 += y * y;
            }
            s1 = wred16_sum(s1); s2 = wred16_sum(s2);
            if (l15 == 0){
                int rr = (mt << 4) + (lg << 2) + r;
                red[rr][w][0] = s1; red[rr][w][1] = s2;
            }
        }
    }
    __syncthreads();
    float gv[4], bb[4];
    #pragma unroll
    for (int nt = 0; nt < 4; nt++){
        gv[nt] = b2f(g[n0 + (nt << 4) + l15]);
        bb[nt] = b2f(bta[n0 + (nt << 4) + l15]);
    }
    #pragma unroll
    for (int mt = 0; mt < 4; mt++){
        #pragma unroll
        for (int r = 0; r < 4; r++){
            int rr = (mt << 4) + (lg << 2) + r;
            int row = m0 + rr;
            float S1 = red[rr][0][0] + red[rr][1][0] + red[rr][2][0] + red[rr][3][0];
            float S2 = red[rr][0][1] + red[rr][1][1] + red[rr][2][1] + red[rr][3][1];
            float mu = S1 * (1.0f / 256.0f);
            float var = S2 * (1.0f / 256.0f) - mu * mu;
            float rs = rsqrtf(var + 1e-5f);
            #pragma unroll
            for (int nt = 0; nt < 4; nt++){
                int col = n0 + (nt << 4) + l15;
                SRC[(size_t)row * 256 + col] = f2b((acc[mt][nt][r] - mu) * rs * gv[nt] + bb[nt]);
            }
        }
    }
}

// =======================================================================
// geo8: geo7 structure WITHOUT embed fusion (AV-MFMA + C-layout LNs kept).
// Writes only cols 192..255 (geo output); embed kernels handle the rest.
// =======================================================================
#define GX1(r,b) (((((r) << 7) | (b))) ^ (((r) & 7) << 4))
#define GH1(r,b) (((((r) << 8) | (b))) ^ (((r) & 7) << 4))

__global__ __launch_bounds__(64) void geo8_kernel(
    const int* __restrict__ src_qk, const int* __restrict__ tgt_qk,
    const u16* __restrict__ emb,
    const u16* __restrict__ w1f, const u16* __restrict__ b1,
    const u16* __restrict__ w2f, const u16* __restrict__ b2,
    const u16* __restrict__ ln1g, const u16* __restrict__ ln1b,
    const u16* __restrict__ ln2g, const u16* __restrict__ ln2b,
    u16* __restrict__ SRC, u16* __restrict__ TGT)
{
    __shared__ __align__(16) u16 xs[16 * 64];     // 2048 B (GX1)
    __shared__ __align__(16) u16 uni[2560];       // 5120 B: hs (GH1) / xT[64][40]
    __shared__ __align__(16) u16 PA[16 * 40];     // 1280 B
    __shared__ __align__(16) float st[16][2];     // 128 B

    int seq = blockIdx.x;
    const int* qk = src_qk;
    u16* outp = SRC;
    if (seq >= 51200){ seq -= 51200; qk = tgt_qk; outp = TGT; }

    const int lane = threadIdx.x;
    const int g = lane >> 4, m = lane & 15;

    v8s ones;
    #pragma unroll
    for (int j = 0; j < 8; j++) ones[j] = (short)0x3F80;

    u16* xT = uni;   // [64][40]

    for (int i = lane; i < 320; i += 64){
        int r = i / 20, c = 12 + (i % 20);
        PA[r * 40 + c] = 0;
    }
    {
        float dv = __expf(-(float)(lane & 31) * 0.28782313662425572f);
        const bool issin = lane < 32;
        #pragma unroll
        for (int t = 0; t < 12; t++){
            int idx = qk[seq * 12 + t];
            float ang = (float)t * dv;
            float pe = issin ? __sinf(ang) : __cosf(ang);
            u16 bv = f2b(b2f(emb[idx * 64 + lane]) + pe);
            xs[GX1(t, lane << 1) >> 1] = bv;
            xT[lane * 40 + t] = bv;
        }
        #pragma unroll
        for (int r = 12; r < 16; r++) xs[GX1(r, lane << 1) >> 1] = (u16)0;
        #pragma unroll
        for (int k = 12; k < 32; k++) xT[lane * 40 + k] = (u16)0;
    }
    lds_fence();

    float fs = 0.f;

    for (int layer = 0; layer < 2; layer++){
        // ---- scores (self-MFMA) + softmax -> PA ----
        {
            v4f S = {0.f, 0.f, 0.f, 0.f};
            v8s f0 = *(const v8s*)((const char*)xs + GX1(m, (g << 4)));
            v8s f1 = *(const v8s*)((const char*)xs + GX1(m, 64 + (g << 4)));
            S = __builtin_amdgcn_mfma_f32_16x16x32_bf16(f0, f0, S, 0, 0, 0);
            S = __builtin_amdgcn_mfma_f32_16x16x32_bf16(f1, f1, S, 0, 0, 0);
            float ex[4];
            #pragma unroll
            for (int r = 0; r < 4; r++) ex[r] = (m < 12) ? __expf(S[r] * 0.125f) : 0.f;
            #pragma unroll
            for (int r = 0; r < 4; r++){
                float s = wred16_sum(ex[r]);
                PA[((g << 2) + r) * 40 + m] = f2b(ex[r] / s);
            }
        }
        lds_fence();

        // ---- AV via MFMA: C = P @ X ; y = C + residual ----
        float y[4][4];
        {
            v8s pa = *(const v8s*)(PA + m * 40 + (g << 3));
            v4f C[4];
            #pragma unroll
            for (int nt = 0; nt < 4; nt++){
                v8s bfx = *(const v8s*)(xT + ((nt << 4) + m) * 40 + (g << 3));
                C[nt] = __builtin_amdgcn_mfma_f32_16x16x32_bf16(pa, bfx, (v4f){0.f,0.f,0.f,0.f}, 0, 0, 0);
            }
            #pragma unroll
            for (int nt = 0; nt < 4; nt++)
                #pragma unroll
                for (int r = 0; r < 4; r++){
                    int row = (g << 2) + r, col = (nt << 4) + m;
                    y[nt][r] = C[nt][r] + b2f(xs[GX1(row, col << 1) >> 1]);
                }
            #pragma unroll
            for (int nt = 0; nt < 4; nt++)
                #pragma unroll
                for (int r = 0; r < 4; r++){
                    int row = (g << 2) + r, col = (nt << 4) + m;
                    xs[GX1(row, col << 1) >> 1] = f2b(y[nt][r]);
                }
        }
        lds_fence();
        // ---- LN1 stats via MFMA ----
        {
            v4f R = {0.f,0.f,0.f,0.f}, Q = {0.f,0.f,0.f,0.f};
            v8s f0 = *(const v8s*)((const char*)xs + GX1(m, (g << 4)));
            v8s f1 = *(const v8s*)((const char*)xs + GX1(m, 64 + (g << 4)));
            R = __builtin_amdgcn_mfma_f32_16x16x32_bf16(f0, ones, R, 0, 0, 0);
            R = __builtin_amdgcn_mfma_f32_16x16x32_bf16(f1, ones, R, 0, 0, 0);
            Q = __builtin_amdgcn_mfma_f32_16x16x32_bf16(f0, f0, Q, 0, 0, 0);
            Q = __builtin_amdgcn_mfma_f32_16x16x32_bf16(f1, f1, Q, 0, 0, 0);
            if (g == (m >> 2)){ st[m][0] = R[m & 3]; st[m][1] = Q[m & 3]; }
        }
        lds_fence();
        // ---- LN1 normalize (C-layout) -> xs ----
        {
            #pragma unroll
            for (int nt = 0; nt < 4; nt++){
                float g1 = b2f(ln1g[layer * 64 + (nt << 4) + m]);
                float bb1 = b2f(ln1b[layer * 64 + (nt << 4) + m]);
                #pragma unroll
                for (int r = 0; r < 4; r++){
                    int row = (g << 2) + r, col = (nt << 4) + m;
                    float mu = st[row][0] * 0.015625f;
                    float var = st[row][1] * 0.015625f - mu * mu;
                    xs[GX1(row, col << 1) >> 1] = f2b((y[nt][r] - mu) * rsqrtf(var + 1e-5f) * g1 + bb1);
                }
            }
        }
        lds_fence();

        // ---- FFN1 (MFMA) -> hs (aliases uni) ----
        {
            u16* hs = uni;
            v8s a0 = *(const v8s*)((const char*)xs + GX1(m, (g << 4)));
            v8s a1 = *(const v8s*)((const char*)xs + GX1(m, 64 + (g << 4)));
            const u16* wf1 = w1f + layer * 8192;
            #pragma unroll
            for (int nt = 0; nt < 8; nt++){
                v8s bfa = *(const v8s*)(wf1 + (((nt << 1) + 0) << 9) + (lane << 3));
                v8s bfb = *(const v8s*)(wf1 + (((nt << 1) + 1) << 9) + (lane << 3));
                v4f h = {0.f, 0.f, 0.f, 0.f};
                h = __builtin_amdgcn_mfma_f32_16x16x32_bf16(a0, bfa, h, 0, 0, 0);
                h = __builtin_amdgcn_mfma_f32_16x16x32_bf16(a1, bfb, h, 0, 0, 0);
                float bia = b2f(b1[layer * 128 + (nt << 4) + m]);
                #pragma unroll
                for (int r = 0; r < 4; r++)
                    hs[GH1((g << 2) + r, (((nt << 4) | m) << 1)) >> 1] = f2b(fmaxf(h[r] + bia, 0.f));
            }
        }
        lds_fence();

        // ---- FFN2 (MFMA) + residual -> y; write y to xs ----
        {
            const u16* hs = uni;
            v8s ha[4];
            #pragma unroll
            for (int c = 0; c < 4; c++)
                ha[c] = *(const v8s*)((const char*)hs + GH1(m, (c << 6) + (g << 4)));
            lds_fence();
            const u16* wf2 = w2f + layer * 8192;
            #pragma unroll
            for (int nt = 0; nt < 4; nt++){
                v4f o = {0.f, 0.f, 0.f, 0.f};
                #pragma unroll
                for (int c = 0; c < 4; c++){
                    v8s bf = *(const v8s*)(wf2 + ((((nt << 2) + c) << 9) + (lane << 3)));
                    o = __builtin_amdgcn_mfma_f32_16x16x32_bf16(ha[c], bf, o, 0, 0, 0);
                }
                float bo = b2f(b2[layer * 64 + (nt << 4) + m]);
                #pragma unroll
                for (int r = 0; r < 4; r++){
                    int row = (g << 2) + r, col = (nt << 4) + m;
                    y[nt][r] = o[r] + bo + b2f(xs[GX1(row, col << 1) >> 1]);
                }
            }
            #pragma unroll
            for (int nt = 0; nt < 4; nt++)
                #pragma unroll
                for (int r = 0; r < 4; r++){
                    int row = (g << 2) + r, col = (nt << 4) + m;
                    xs[GX1(row, col << 1) >> 1] = f2b(y[nt][r]);
                }
        }
        lds_fence();
        // ---- LN2 stats via MFMA ----
        {
            v4f R = {0.f,0.f,0.f,0.f}, Q = {0.f,0.f,0.f,0.f};
            v8s f0 = *(const v8s*)((const char*)xs + GX1(m, (g << 4)));
            v8s f1 = *(const v8s*)((const char*)xs + GX1(m, 64 + (g << 4)));
            R = __builtin_amdgcn_mfma_f32_16x16x32_bf16(f0, ones, R, 0, 0, 0);
            R = __builtin_amdgcn_mfma_f32_16x16x32_bf16(f1, ones, R, 0, 0, 0);
            Q = __builtin_amdgcn_mfma_f32_16x16x32_bf16(f0, f0, Q, 0, 0, 0);
            Q = __builtin_amdgcn_mfma_f32_16x16x32_bf16(f1, f1, Q, 0, 0, 0);
            if (g == (m >> 2)){ st[m][0] = R[m & 3]; st[m][1] = Q[m & 3]; }
        }
        lds_fence();
        // ---- LN2 normalize: layer0 -> xs + xT ; layer1 -> fs ----
        {
            float xv[4][4];
            #pragma unroll
            for (int nt = 0; nt < 4; nt++){
                float g2 = b2f(ln2g[layer * 64 + (nt << 4) + m]);
                float bb2 = b2f(ln2b[layer * 64 + (nt << 4) + m]);
                #pragma unroll
                for (int r = 0; r < 4; r++){
                    int row = (g << 2) + r;
                    float mu = st[row][0] * 0.015625f;
                    float var = st[row][1] * 0.015625f - mu * mu;
                    xv[nt][r] = (y[nt][r] - mu) * rsqrtf(var + 1e-5f) * g2 + bb2;
                }
            }
            if (layer == 0){
                #pragma unroll
                for (int nt = 0; nt < 4; nt++)
                    #pragma unroll
                    for (int r = 0; r < 4; r++){
                        int row = (g << 2) + r, col = (nt << 4) + m;
                        u16 bv = f2b(xv[nt][r]);
                        xs[GX1(row, col << 1) >> 1] = bv;
                        xT[col * 40 + row] = bv;
                    }
            } else {
                float tot[4];
                #pragma unroll
                for (int nt = 0; nt < 4; nt++){
                    float p = 0.f;
                    if (g < 3){
                        #pragma unroll
                        for (int r = 0; r < 4; r++) p += xv[nt][r];
                    }
                    p += __shfl_xor(p, 16, 64);
                    p += __shfl_xor(p, 32, 64);
                    tot[nt] = p;
                }
                fs = (g == 0) ? tot[0] : (g == 1) ? tot[1] : (g == 2) ? tot[2] : tot[3];
            }
        }
        lds_fence();
    }
    outp[(size_t)seq * 256 + 192 + lane] = f2b(fs * (1.0f / 12.0f));
}

__global__ __launch_bounds__(256) void embed_src_kernel(
    const int* __restrict__ poi, const float* __restrict__ timev,
    const void* __restrict__ emb_poi, u16* __restrict__ src,
    const int* __restrict__ flag)
{
    const int bl = blockIdx.x;
    const int d  = threadIdx.x;
    const int b  = bl / 100;
    const int isbf = *flag;
    float t0 = timev[b * 100];
    float tN = timev[b * 100 + 99];
    float tv = timev[bl];
    float pos = (tv - t0) / (tN - t0 + 1e-9f) * 99.0f;
    int j = d & 127;
    float dvv = __expf(-(float)j * 0.07195578415606393f);
    float ang = pos * dvv;
    float pe = (d < 128) ? __sinf(ang) : __cosf(ang);
    size_t off = (size_t)bl * 256 + d;
    float val = (d < 192) ? ldm(emb_poi, (size_t)poi[bl] * 192 + d, isbf) : b2f(src[off]);
    src[off] = f2b(val + pe);
}

__global__ __launch_bounds__(256) void embed_tgt_kernel(
    const int* __restrict__ poi, const void* __restrict__ emb_poi,
    u16* __restrict__ tgt, int n, const int* __restrict__ flag)
{
    int i = blockIdx.x * 256 + threadIdx.x;
    if (i >= n * 192) return;
    int bt = i / 192; int d = i - bt * 192;
    tgt[(size_t)bt * 256 + d] = f2b(ldm(emb_poi, (size_t)poi[bt] * 192 + d, *flag));
}

__global__ __launch_bounds__(256) void relmax_kernel(
    const void* __restrict__ tm, const void* __restrict__ gm,
    float* __restrict__ relm, const int* __restrict__ flag)
{
    const int b = blockIdx.x, tid = threadIdx.x;
    const int isbf = *flag;
    size_t base = (size_t)b * 10000;
    float tmax = -1e30f, gmax = -1e30f;
    for (int i = tid; i < 10000; i += 256){
        tmax = fmaxf(tmax, fminf(ldm(tm, base + i, isbf), 0.5f));
        gmax = fmaxf(gmax, fminf(ldm(gm, base + i, isbf), 0.5f));
    }
    tmax = wred_max(tmax); gmax = wred_max(gmax);
    __shared__ float st[4], sg[4];
    if ((tid & 63) == 0){ st[tid >> 6] = tmax; sg[tid >> 6] = gmax; }
    __syncthreads();
    if (tid == 0){
        relm[b * 2]     = fmaxf(fmaxf(st[0], st[1]), fmaxf(st[2], st[3]));
        relm[b * 2 + 1] = fmaxf(fmaxf(sg[0], sg[1]), fmaxf(sg[2], sg[3]));
    }
}

// =======================================================================
// attn: MFMA scores from global Q/K; vector AV; fused residual+LN1.
// =======================================================================
__global__ __launch_bounds__(256) void attn_kernel(
    const u16* __restrict__ QB, const u16* __restrict__ Kg, const u16* __restrict__ Vg,
    u16* __restrict__ SRC,
    const void* __restrict__ tmp_, const void* __restrict__ gmp_,
    const float* __restrict__ relm,
    const u16* __restrict__ lng, const u16* __restrict__ lnb,
    const int* __restrict__ flag)
{
    __shared__ __align__(16) u16 KV[100][264];
    __shared__ __align__(16) u16 Amat[50][112];

    const int blk = blockIdx.x;
    const int b = blk >> 1, h = blk & 1;
    const int tid = threadIdx.x;
    const int w = tid >> 6, lane = tid & 63;
    const int l15 = lane & 15, lg = lane >> 4;
    const int q0 = h * 50;
    const int nk = q0 + 50;
    const int isbf = *flag;
    const float tmax = relm[b * 2], gmax = relm[b * 2 + 1];

    const u16* Vb = Vg + (size_t)b * 100 * 256;
    for (int i = tid; i < nk * 128; i += 256){
        int row = i >> 7, c2 = (i & 127) * 2;
        *(ushort2*)&KV[row][c2] = *(const ushort2*)(Vb + row * 256 + c2);
    }

    const int ntc = (h == 0) ? 4 : 7;
    const int qrow = q0 + w * 16 + l15;
    const u16* Aq = QB + ((size_t)b * 100 + (qrow < 100 ? qrow : 99)) * 256 + (lg << 3);
    const u16* Kb = Kg + (size_t)b * 100 * 256;
    v4f S[7];
    #pragma unroll
    for (int nt = 0; nt < 7; nt++) S[nt] = (v4f){0.f, 0.f, 0.f, 0.f};
    const u16* Bp[7];
    for (int nt = 0; nt < ntc; nt++){
        int kt = nt * 16 + l15;
        Bp[nt] = Kb + (size_t)(kt < 100 ? kt : 99) * 256 + (lg << 3);
    }
    for (int c = 0; c < 8; c++){
        v8s af = *(const v8s*)(Aq + (c << 5));
        for (int nt = 0; nt < ntc; nt++){
            v8s bf = *(const v8s*)(Bp[nt] + (c << 5));
            S[nt] = __builtin_amdgcn_mfma_f32_16x16x32_bf16(af, bf, S[nt], 0, 0, 0);
        }
    }

    float P[7][4];
    #pragma unroll
    for (int r = 0; r < 4; r++){
        int qrel = w * 16 + (lg << 2) + r;
        int q = q0 + qrel;
        int qc = q < 100 ? q : 99;
        size_t rbase = ((size_t)b * 100 + qc) * 100;
        float sv[7];
        float mx = -1e30f;
        for (int nt = 0; nt < ntc; nt++){
            int kt = nt * 16 + l15;
            int ktc = kt < 100 ? kt : 99;
            float rel = (tmax - fminf(ldm(tmp_, rbase + ktc, isbf), 0.5f))
                      + (gmax - fminf(ldm(gmp_, rbase + ktc, isbf), 0.5f));
            float s = S[nt][r] * 0.0625f + rel;
            if (kt > q) s = -1e30f;
            sv[nt] = s;
            mx = fmaxf(mx, s);
        }
        mx = wred16_max(mx);
        float sum = 0.f;
        for (int nt = 0; nt < ntc; nt++){ sv[nt] = __expf(sv[nt] - mx); sum += sv[nt]; }
        sum = wred16_sum(sum);
        float inv = 1.0f / sum;
        for (int nt = 0; nt < ntc; nt++) P[nt][r] = sv[nt] * inv;
    }
    #pragma unroll
    for (int r = 0; r < 4; r++){
        int qrel = w * 16 + (lg << 2) + r;
        if (qrel < 50){
            for (int nt = 0; nt < ntc; nt++)
                Amat[qrel][nt * 16 + l15] = f2b(P[nt][r]);
        }
    }
    __syncthreads();

    for (int qq = 0; qq < 13; qq++){
        const int qr = qq * 4 + w;
        const int q  = q0 + qr;
        if (qr < 50){
            float o00 = 0.f, o01 = 0.f, o10 = 0.f, o11 = 0.f;
            const int kfull = (q + 1) & ~7;
            for (int k8 = 0; k8 < (kfull >> 3); k8++){
                uint4 av = *(const uint4*)&Amat[qr][k8 * 8];
                float p[8] = { lo2f(av.x), hi2f(av.x), lo2f(av.y), hi2f(av.y),
                               lo2f(av.z), hi2f(av.z), lo2f(av.w), hi2f(av.w) };
                #pragma unroll
                for (int j = 0; j < 8; j++){
                    int k = k8 * 8 + j;
                    u32 v0 = *(const u32*)&KV[k][2 * lane];
                    u32 v1 = *(const u32*)&KV[k][128 + 2 * lane];
                    o00 += p[j] * lo2f(v0); o01 += p[j] * hi2f(v0);
                    o10 += p[j] * lo2f(v1); o11 += p[j] * hi2f(v1);
                }
            }
            for (int k = kfull; k <= q; k++){
                float a = b2f(Amat[qr][k]);
                u32 v0 = *(const u32*)&KV[k][2 * lane];
                u32 v1 = *(const u32*)&KV[k][128 + 2 * lane];
                o00 += a * lo2f(v0); o01 += a * hi2f(v0);
                o10 += a * lo2f(v1); o11 += a * hi2f(v1);
            }
            u16* Sg = SRC + ((size_t)b * 100 + q) * 256;
            u32 s0v = *(const u32*)&Sg[2 * lane];
            u32 s1v = *(const u32*)&Sg[128 + 2 * lane];
            float y0 = o00 + lo2f(s0v), y1 = o01 + hi2f(s0v);
            float y2 = o10 + lo2f(s1v), y3 = o11 + hi2f(s1v);
            float s1 = y0 + y1 + y2 + y3;
            float s2 = y0*y0 + y1*y1 + y2*y2 + y3*y3;
            s1 = wred_sum(s1); s2 = wred_sum(s2);
            float mu = s1 * (1.0f / 256.0f);
            float var = s2 * (1.0f / 256.0f) - mu * mu;
            float rs = rsqrtf(var + 1e-5f);
            u32 g0 = *(const u32*)&lng[2 * lane], g1 = *(const u32*)&lng[128 + 2 * lane];
            u32 b0 = *(const u32*)&lnb[2 * lane], b1 = *(const u32*)&lnb[128 + 2 * lane];
            ushort2 w0, w1;
            w0.x = f2b((y0 - mu) * rs * lo2f(g0) + lo2f(b0));
            w0.y = f2b((y1 - mu) * rs * hi2f(g0) + hi2f(b0));
            w1.x = f2b((y2 - mu) * rs * lo2f(g1) + lo2f(b1));
            w1.y = f2b((y3 - mu) * rs * hi2f(g1) + hi2f(b1));
            *(ushort2*)&Sg[2 * lane]       = w0;
            *(ushort2*)&Sg[128 + 2 * lane] = w1;
        }
    }
}

__global__ __launch_bounds__(256) void decv_kernel(
    const u16* __restrict__ SRC, const u16* __restrict__ wv, float* __restrict__ VS)
{
    __shared__ float sv[256];
    const int b = blockIdx.x, n = threadIdx.x;
    const u16* s = SRC + ((size_t)b * 100 + 99) * 256;
    sv[n] = b2f(s[n]);
    __syncthreads();
    float acc = 0.f;
    for (int d = 0; d < 256; d++) acc += sv[d] * b2f(wv[d * 256 + n]);
    VS[(size_t)b * 256 + n] = acc;
}

__global__ __launch_bounds__(256) void decfinal_kernel(
    const u16* __restrict__ TGT, const u16* __restrict__ SRC,
    const float* __restrict__ VS,
    const u16* __restrict__ dlg, const u16* __restrict__ dlb,
    const u16* __restrict__ ng,  const u16* __restrict__ nb,
    void* __restrict__ outp, const int* __restrict__ flag)
{
    __shared__ float red2[4][2];
    __shared__ float red1[4];
    const int bt = blockIdx.x, d = threadIdx.x;
    const int b = bt / 101;
    float tg  = b2f(TGT[(size_t)bt * 256 + d]);
    float mem = b2f(SRC[((size_t)b * 100 + 99) * 256 + d]);
    float y = tg + VS[(size_t)b * 256 + d];
    float a = y, bb = y * y;
    block_sum2(a, bb, red2, d);
    float mu1 = a * (1.0f / 256.0f);
    float v1 = bb * (1.0f / 256.0f) - mu1 * mu1;
    float x = (y - mu1) * rsqrtf(v1 + 1e-5f) * b2f(dlg[d]) + b2f(dlb[d]);
    float y2 = x + mem;
    float a2 = y2, b2_ = y2 * y2;
    block_sum2(a2, b2_, red2, d);
    float mu2 = a2 * (1.0f / 256.0f);
    float v2 = b2_ * (1.0f / 256.0f) - mu2 * mu2;
    float o = (y2 - mu2) * rsqrtf(v2 + 1e-5f) * b2f(ng[d]) + b2f(nb[d]);
    float tot = block_sum256(o * tg, red1, d);
    if (d == 0){
        if (*flag) ((u16*)outp)[bt] = f2b(tot);
        else       ((float*)outp)[bt] = tot;
    }
}

extern "C" void kernel_launch(void* const* d_in, const int* in_sizes, int n_in,
                              void* d_out, int out_size, void* d_ws, size_t ws_size,
                              hipStream_t stream)
{
    char* ws = (char*)d_ws;
    size_t off = 0;
    auto AL = [&](size_t bytes){ size_t o = off; off += (bytes + 255) & ~(size_t)255; return o; };
    const size_t FLAGO = AL(4);
    const size_t CTIME = AL(51200 * 4);
    const size_t CEQK  = AL(262144 * 2);
    const size_t CGW1  = AL(16384 * 2), CGB1 = AL(256 * 2), CGW2 = AL(16384 * 2), CGB2 = AL(128 * 2);
    const size_t CGL1G = AL(128 * 2), CGL1B = AL(128 * 2), CGL2G = AL(128 * 2), CGL2B = AL(128 * 2);
    const size_t CEWQ  = AL(131072 * 2), CEWK = AL(131072 * 2), CEWV = AL(131072 * 2);
    const size_t CEW1  = AL(262144 * 2), CEB1 = AL(1024 * 2), CEW2 = AL(262144 * 2), CEB2 = AL(512 * 2);
    const size_t CEL1G = AL(512 * 2), CEL1B = AL(512 * 2), CEL2G = AL(512 * 2), CEL2B = AL(512 * 2);
    const size_t CDWV  = AL(65536 * 2), CDLG = AL(256 * 2), CDLB = AL(256 * 2), CNG = AL(256 * 2), CNB = AL(256 * 2);
    const size_t W1FO  = AL(16384 * 2), W2FO = AL(16384 * 2);
    const size_t QKVFO = AL(786432 * 2);
    const size_t W1FEO = AL(524288 * 2);
    const size_t W2FEO = AL(524288 * 2);
    const size_t RELMO = AL(512 * 2 * 4);
    const size_t VSO   = AL(512 * 256 * 4);
    const size_t SRCO  = AL((size_t)51200 * 256 * 2);
    const size_t TGTO  = AL((size_t)51712 * 256 * 2);
    const size_t B1O   = AL((size_t)51200 * 256 * 2);
    const size_t B2O   = AL((size_t)51200 * 256 * 2);
    const size_t B3O   = AL((size_t)51200 * 256 * 2);
    (void)ws_size; (void)in_sizes; (void)n_in; (void)out_size;

    int*   FLAG = (int*)(ws + FLAGO);
    float* CT   = (float*)(ws + CTIME);
    u16 *cEQK=(u16*)(ws+CEQK), *cGW1=(u16*)(ws+CGW1), *cGB1=(u16*)(ws+CGB1), *cGW2=(u16*)(ws+CGW2),
        *cGB2=(u16*)(ws+CGB2), *cGL1G=(u16*)(ws+CGL1G), *cGL1B=(u16*)(ws+CGL1B), *cGL2G=(u16*)(ws+CGL2G),
        *cGL2B=(u16*)(ws+CGL2B), *cEWQ=(u16*)(ws+CEWQ), *cEWK=(u16*)(ws+CEWK), *cEWV=(u16*)(ws+CEWV),
        *cEW1=(u16*)(ws+CEW1), *cEB1=(u16*)(ws+CEB1), *cEW2=(u16*)(ws+CEW2), *cEB2=(u16*)(ws+CEB2),
        *cEL1G=(u16*)(ws+CEL1G), *cEL1B=(u16*)(ws+CEL1B), *cEL2G=(u16*)(ws+CEL2G), *cEL2B=(u16*)(ws+CEL2B),
        *cDWV=(u16*)(ws+CDWV), *cDLG=(u16*)(ws+CDLG), *cDLB=(u16*)(ws+CDLB), *cNG=(u16*)(ws+CNG),
        *cNB=(u16*)(ws+CNB);
    u16* W1F   = (u16*)(ws + W1FO);
    u16* W2F   = (u16*)(ws + W2FO);
    u16* QKVF  = (u16*)(ws + QKVFO);
    u16* W1FE  = (u16*)(ws + W1FEO);
    u16* W2FE  = (u16*)(ws + W2FEO);
    float* RELM = (float*)(ws + RELMO);
    float* VS   = (float*)(ws + VSO);
    u16* SRC = (u16*)(ws + SRCO);
    u16* TGT = (u16*)(ws + TGTO);
    u16* B1  = (u16*)(ws + B1O);
    u16* B2  = (u16*)(ws + B2O);
    u16* B3  = (u16*)(ws + B3O);
    u16* Hh  = B2;

    const int* src_poi = (const int*)d_in[0];
    const int* src_qk  = (const int*)d_in[1];
    const int* tgt_poi = (const int*)d_in[7];
    const int* tgt_qk  = (const int*)d_in[8];

    probe_kernel<<<1, 64, 0, stream>>>((const u32*)d_in[38], FLAG);

    ConvArgs ca;
    const int srcidx[NSEG] = {13,14,15,16,17,18,19,20,21,22,23,24,25,26,27,28,29,30,31,32,35,36,37,38,39};
    u16* dsts[NSEG] = {cEQK,cGW1,cGB1,cGW2,cGB2,cGL1G,cGL1B,cGL2G,cGL2B,cEWQ,cEWK,cEWV,
                       cEW1,cEB1,cEW2,cEB2,cEL1G,cEL1B,cEL2G,cEL2B,cDWV,cDLG,cDLB,cNG,cNB};
    const int ns[NSEG] = {262144,16384,256,16384,128,128,128,128,128,131072,131072,131072,
                          262144,1024,262144,512,512,512,512,512,65536,256,256,256,256};
    for (int i = 0; i < NSEG; i++){ ca.src[i] = d_in[srcidx[i]]; ca.dst[i] = dsts[i]; ca.n[i] = ns[i]; }
    convert_kernel<<<dim3(1024, NSEG), 256, 0, stream>>>(ca, FLAG);
    convert_time_kernel<<<200, 256, 0, stream>>>(d_in[2], CT, FLAG);

    packfrag_kernel<<<64, 256, 0, stream>>>(cGW1, W1F, 64, 128, 2);
    packfrag_kernel<<<64, 256, 0, stream>>>(cGW2, W2F, 128, 64, 2);
    packfrag3_kernel<<<3072, 256, 0, stream>>>(cEWQ, cEWK, cEWV, QKVF);
    packfrag_kernel<<<1024, 256, 0, stream>>>(cEW1, W1FE, 256, 512, 2);
    packfrag_kernel<<<1024, 256, 0, stream>>>(cEW2, W2FE, 512, 256, 2);

    geo8_kernel<<<102912, 64, 0, stream>>>(src_qk, tgt_qk, cEQK, W1F, cGB1, W2F, cGB2,
                                           cGL1G, cGL1B, cGL2G, cGL2B, SRC, TGT);
    embed_src_kernel<<<51200, 256, 0, stream>>>(src_poi, CT, d_in[12], SRC, FLAG);
    embed_tgt_kernel<<<(51712 * 192 + 255) / 256, 256, 0, stream>>>(tgt_poi, d_in[12], TGT, 51712, FLAG);
    relmax_kernel<<<512, 256, 0, stream>>>(d_in[3], d_in[4], RELM, FLAG);

    for (int i = 0; i < 2; i++){
        gemm2_kernel<0,1><<<dim3(400, 6), 256, 0, stream>>>(SRC, QKVF + (size_t)i * 196608, nullptr,
                                                            B1, B2, B3, 51200, 768, 256);
        attn_kernel<<<1024, 256, 0, stream>>>(B1, B2, B3, SRC, d_in[3], d_in[4], RELM,
                                              cEL1G + i * 256, cEL1B + i * 256, FLAG);
        gemm2_kernel<1,0><<<dim3(400, 4), 256, 0, stream>>>(SRC, W1FE + (size_t)i * 131072, cEB1 + i * 512,
                                                            Hh, nullptr, nullptr, 51200, 512, 256);
        gemm3_kernel<<<800, 256, 0, stream>>>(Hh, W2FE + (size_t)i * 131072, cEB2 + i * 256,
                                              SRC, cEL2G + i * 256, cEL2B + i * 256);
    }

    decv_kernel<<<512, 256, 0, stream>>>(SRC, cDWV, VS);
    decfinal_kernel<<<51712, 256, 0, stream>>>(TGT, SRC, VS, cDLG, cDLB, cNG, cNB, d_out, FLAG);
}

// Round 13
// 1273.176 us; speedup vs baseline: 1.1379x; 1.1379x over previous
//
#include <hip/hip_runtime.h>
#include <hip/hip_bf16.h>
#include <stdint.h>

typedef unsigned short u16;
typedef unsigned int   u32;
typedef __attribute__((ext_vector_type(8))) short v8s;
typedef __attribute__((ext_vector_type(4))) float v4f;

__device__ __forceinline__ float b2f(u16 u){ return __uint_as_float(((u32)u) << 16); }
__device__ __forceinline__ float lo2f(u32 u){ return __uint_as_float(u << 16); }
__device__ __forceinline__ float hi2f(u32 u){ return __uint_as_float(u & 0xffff0000u); }
__device__ __forceinline__ u16 f2b(float f){
    u32 x = __float_as_uint(f);
    u32 r = (x + 0x7fffu + ((x >> 16) & 1u)) >> 16;
    return (u16)r;
}
__device__ __forceinline__ float ldm(const void* p, size_t i, int isbf){
    return isbf ? b2f(((const u16*)p)[i]) : ((const float*)p)[i];
}
__device__ __forceinline__ float wred_sum(float v){
    #pragma unroll
    for (int o = 32; o > 0; o >>= 1) v += __shfl_xor(v, o, 64);
    return v;
}
__device__ __forceinline__ float wred_max(float v){
    #pragma unroll
    for (int o = 32; o > 0; o >>= 1) v = fmaxf(v, __shfl_xor(v, o, 64));
    return v;
}
__device__ __forceinline__ float wred16_sum(float v){
    #pragma unroll
    for (int o = 8; o > 0; o >>= 1) v += __shfl_xor(v, o, 64);
    return v;
}
__device__ __forceinline__ float wred16_max(float v){
    #pragma unroll
    for (int o = 8; o > 0; o >>= 1) v = fmaxf(v, __shfl_xor(v, o, 64));
    return v;
}
__device__ __forceinline__ float block_sum256(float v, float* red, int tid){
    float s = wred_sum(v);
    __syncthreads();
    if ((tid & 63) == 0) red[tid >> 6] = s;
    __syncthreads();
    return red[0] + red[1] + red[2] + red[3];
}
__device__ __forceinline__ void block_sum2(float& a, float& b, float (*red)[2], int tid){
    a = wred_sum(a); b = wred_sum(b);
    __syncthreads();
    if ((tid & 63) == 0){ red[tid >> 6][0] = a; red[tid >> 6][1] = b; }
    __syncthreads();
    a = red[0][0] + red[1][0] + red[2][0] + red[3][0];
    b = red[0][1] + red[1][1] + red[2][1] + red[3][1];
}
__device__ __forceinline__ void lds_fence(){
    asm volatile("s_waitcnt lgkmcnt(0)" ::: "memory");
    __builtin_amdgcn_sched_barrier(0);
}

__global__ void probe_kernel(const u32* __restrict__ ng, int* __restrict__ flag){
    if (threadIdx.x == 0) *flag = (ng[0] == 0x3F803F80u) ? 1 : 0;
}

#define NSEG 25
struct ConvArgs {
    const void* src[NSEG];
    u16*        dst[NSEG];
    int         n[NSEG];
};
__global__ __launch_bounds__(256) void convert_kernel(ConvArgs a, const int* __restrict__ flag){
    int seg = blockIdx.y;
    int i = blockIdx.x * 256 + threadIdx.x;
    if (i >= a.n[seg]) return;
    int isbf = *flag;
    a.dst[seg][i] = f2b(ldm(a.src[seg], i, isbf));
}
__global__ __launch_bounds__(256) void convert_time_kernel(const void* __restrict__ src,
                                                           float* __restrict__ dst,
                                                           const int* __restrict__ flag){
    int i = blockIdx.x * 256 + threadIdx.x;
    if (i >= 51200) return;
    dst[i] = ldm(src, i, *flag);
}

// pack [nlayer][K][N] bf16 weights into MFMA B-fragment order
__global__ __launch_bounds__(256) void packfrag_kernel(
    const u16* __restrict__ W, u16* __restrict__ out, int K, int N, int nlayer)
{
    int i = blockIdx.x * 256 + threadIdx.x;
    int total = nlayer * K * N;
    if (i >= total) return;
    int j = i & 7, lane = (i >> 3) & 63, fc = i >> 9;
    int CT = K >> 5, NT = N >> 4;
    int c = fc % CT, nt = (fc / CT) % NT, layer = fc / (CT * NT);
    int k = c * 32 + ((lane >> 4) << 3) + j, n = (nt << 4) + (lane & 15);
    out[i] = W[(layer * K + k) * N + n];
}

// pack QKV (3x [2][256][256]) into one fragment buffer as N=768
__global__ __launch_bounds__(256) void packfrag3_kernel(
    const u16* __restrict__ Wq, const u16* __restrict__ Wk, const u16* __restrict__ Wv,
    u16* __restrict__ out)
{
    int i = blockIdx.x * 256 + threadIdx.x;
    if (i >= 786432) return;
    int j = i & 7, lane = (i >> 3) & 63, fc = i >> 9;
    int c = fc & 7, nt = (fc >> 3) % 48, layer = fc / (8 * 48);
    int k = c * 32 + ((lane >> 4) << 3) + j, n = (nt << 4) + (lane & 15);
    const u16* W = (n < 256) ? Wq : (n < 512) ? Wk : Wv;
    out[i] = W[(layer * 256 + k) * 256 + (n & 255)];
}

// =======================================================================
// gemm2: LDS-free MFMA GEMM
// =======================================================================
template<int ACT, int SPLIT>
__global__ __launch_bounds__(256) void gemm2_kernel(
    const u16* __restrict__ A, const u16* __restrict__ Bf,
    const u16* __restrict__ bias,
    u16* __restrict__ C0, u16* __restrict__ C1, u16* __restrict__ C2,
    int M, int N, int K)
{
    const int tid = threadIdx.x, w = tid >> 6, lane = tid & 63;
    const int wm = w >> 1, wn = w & 1;
    const int m0 = blockIdx.x * 128 + wm * 64;
    const int n0 = blockIdx.y * 128 + wn * 64;
    const int CT = K >> 5;
    const int l15 = lane & 15, lg = lane >> 4;

    v4f acc[4][4];
    #pragma unroll
    for (int mt = 0; mt < 4; mt++)
        #pragma unroll
        for (int nt = 0; nt < 4; nt++) acc[mt][nt] = (v4f){0.f, 0.f, 0.f, 0.f};

    const u16* Arow = A + (size_t)(m0 + l15) * K + (lg << 3);
    const u16* Bbase = Bf + (((size_t)(n0 >> 4) * CT) << 9) + (lane << 3);

    for (int c = 0; c < CT; c++){
        v8s bfr[4];
        #pragma unroll
        for (int nt = 0; nt < 4; nt++)
            bfr[nt] = *(const v8s*)(Bbase + (((size_t)(nt * CT + c)) << 9));
        #pragma unroll
        for (int mt = 0; mt < 4; mt++){
            v8s af = *(const v8s*)(Arow + (size_t)(mt << 4) * K + (c << 5));
            #pragma unroll
            for (int nt = 0; nt < 4; nt++)
                acc[mt][nt] = __builtin_amdgcn_mfma_f32_16x16x32_bf16(af, bfr[nt], acc[mt][nt], 0, 0, 0);
        }
    }

    #pragma unroll
    for (int nt = 0; nt < 4; nt++){
        int colbase = n0 + (nt << 4);
        float bv = bias ? b2f(bias[colbase + l15]) : 0.f;
        u16* Cp; int cw;
        if (SPLIT){
            int nb = colbase >> 8;
            Cp = (nb == 0) ? C0 : (nb == 1) ? C1 : C2;
            cw = 256;
            colbase &= 255;
        } else { Cp = C0; cw = N; }
        #pragma unroll
        for (int mt = 0; mt < 4; mt++)
            #pragma unroll
            for (int r = 0; r < 4; r++){
                int row = m0 + (mt << 4) + (lg << 2) + r;
                float v = acc[mt][nt][r] + bv;
                if (ACT) v = fmaxf(v, 0.f);
                Cp[(size_t)row * cw + colbase + l15] = f2b(v);
            }
    }
}

// =======================================================================
// gemm3: FFN2 + residual + LN fused. Block = 64 rows x 256 cols, 4 waves
// =======================================================================
__global__ __launch_bounds__(256) void gemm3_kernel(
    const u16* __restrict__ A, const u16* __restrict__ Bf,
    const u16* __restrict__ bias, u16* __restrict__ SRC,
    const u16* __restrict__ g, const u16* __restrict__ bta)
{
    __shared__ float red[64][4][2];
    const int tid = threadIdx.x, w = tid >> 6, lane = tid & 63;
    const int l15 = lane & 15, lg = lane >> 4;
    const int m0 = blockIdx.x * 64;
    const int n0 = w * 64;
    const int CT = 16;   // K=512

    v4f acc[4][4];
    #pragma unroll
    for (int mt = 0; mt < 4; mt++)
        #pragma unroll
        for (int nt = 0; nt < 4; nt++) acc[mt][nt] = (v4f){0.f, 0.f, 0.f, 0.f};

    const u16* Arow = A + (size_t)(m0 + l15) * 512 + (lg << 3);
    const u16* Bbase = Bf + (((size_t)(n0 >> 4) * CT) << 9) + (lane << 3);

    for (int c = 0; c < CT; c++){
        v8s bfr[4];
        #pragma unroll
        for (int nt = 0; nt < 4; nt++)
            bfr[nt] = *(const v8s*)(Bbase + (((size_t)(nt * CT + c)) << 9));
        #pragma unroll
        for (int mt = 0; mt < 4; mt++){
            v8s af = *(const v8s*)(Arow + (size_t)(mt << 4) * 512 + (c << 5));
            #pragma unroll
            for (int nt = 0; nt < 4; nt++)
                acc[mt][nt] = __builtin_amdgcn_mfma_f32_16x16x32_bf16(af, bfr[nt], acc[mt][nt], 0, 0, 0);
        }
    }

    float bv[4];
    #pragma unroll
    for (int nt = 0; nt < 4; nt++) bv[nt] = b2f(bias[n0 + (nt << 4) + l15]);
    #pragma unroll
    for (int mt = 0; mt < 4; mt++){
        #pragma unroll
        for (int r = 0; r < 4; r++){
            int row = m0 + (mt << 4) + (lg << 2) + r;
            float s1 = 0.f, s2 = 0.f;
            #pragma unroll
            for (int nt = 0; nt < 4; nt++){
                int col = n0 + (nt << 4) + l15;
                float y = acc[mt][nt][r] + bv[nt] + b2f(SRC[(size_t)row * 256 + col]);
                acc[mt][nt][r] = y;
                s1 += y; s2 += y * y;
            }
            s1 = wred16_sum(s1); s2 = wred16_sum(s2);
            if (l15 == 0){
                int rr = (mt << 4) + (lg << 2) + r;
                red[rr][w][0] = s1; red[rr][w][1] = s2;
            }
        }
    }
    __syncthreads();
    float gv[4], bb[4];
    #pragma unroll
    for (int nt = 0; nt < 4; nt++){
        gv[nt] = b2f(g[n0 + (nt << 4) + l15]);
        bb[nt] = b2f(bta[n0 + (nt << 4) + l15]);
    }
    #pragma unroll
    for (int mt = 0; mt < 4; mt++){
        #pragma unroll
        for (int r = 0; r < 4; r++){
            int rr = (mt << 4) + (lg << 2) + r;
            int row = m0 + rr;
            float S1 = red[rr][0][0] + red[rr][1][0] + red[rr][2][0] + red[rr][3][0];
            float S2 = red[rr][0][1] + red[rr][1][1] + red[rr][2][1] + red[rr][3][1];
            float mu = S1 * (1.0f / 256.0f);
            float var = S2 * (1.0f / 256.0f) - mu * mu;
            float rs = rsqrtf(var + 1e-5f);
            #pragma unroll
            for (int nt = 0; nt < 4; nt++){
                int col = n0 + (nt << 4) + l15;
                SRC[(size_t)row * 256 + col] = f2b((acc[mt][nt][r] - mu) * rs * gv[nt] + bb[nt]);
            }
        }
    }
}

// =======================================================================
// geo6: one seq per 64-lane wave; MFMA-based LN stats; merged SRC+TGT.
// =======================================================================
#define GX1(r,b) (((((r) << 7) | (b))) ^ (((r) & 7) << 4))
#define GH1(r,b) (((((r) << 8) | (b))) ^ (((r) & 7) << 4))

__global__ __launch_bounds__(64) void geo6_kernel(
    const int* __restrict__ src_qk, const int* __restrict__ tgt_qk,
    const u16* __restrict__ emb,
    const u16* __restrict__ w1f, const u16* __restrict__ b1,
    const u16* __restrict__ w2f, const u16* __restrict__ b2,
    const u16* __restrict__ ln1g, const u16* __restrict__ ln1b,
    const u16* __restrict__ ln2g, const u16* __restrict__ ln2b,
    u16* __restrict__ SRC, u16* __restrict__ TGT)
{
    __shared__ __align__(16) u16 xs[16 * 64];
    __shared__ __align__(16) u16 hs[16 * 128];
    __shared__ __align__(16) float Ps[16][20];

    int seq = blockIdx.x;
    const int* qk = src_qk;
    u16* outp = SRC;
    if (seq >= 51200){ qk = tgt_qk; outp = TGT; seq -= 51200; }

    const int lane = threadIdx.x;
    const int g = lane >> 4, m = lane & 15;

    v8s ones;
    #pragma unroll
    for (int j = 0; j < 8; j++) ones[j] = (short)0x3F80;

    {
        float dv = __expf(-(float)(lane & 31) * 0.28782313662425572f);
        const bool issin = lane < 32;
        #pragma unroll
        for (int t = 0; t < 12; t++){
            int idx = qk[seq * 12 + t];
            float ang = (float)t * dv;
            float pe = issin ? __sinf(ang) : __cosf(ang);
            xs[GX1(t, lane << 1) >> 1] = f2b(b2f(emb[idx * 64 + lane]) + pe);
        }
        #pragma unroll
        for (int r = 12; r < 16; r++) xs[GX1(r, lane << 1) >> 1] = (u16)0;
    }
    lds_fence();

    float fsum = 0.f;
    const bool isdiag = (g == (m >> 2)) && (m < 12);
    const int dr = m & 3;

    for (int layer = 0; layer < 2; layer++){
        v4f S = {0.f, 0.f, 0.f, 0.f};
        {
            v8s f0 = *(const v8s*)((const char*)xs + GX1(m, (g << 4)));
            v8s f1 = *(const v8s*)((const char*)xs + GX1(m, 64 + (g << 4)));
            S = __builtin_amdgcn_mfma_f32_16x16x32_bf16(f0, f0, S, 0, 0, 0);
            S = __builtin_amdgcn_mfma_f32_16x16x32_bf16(f1, f1, S, 0, 0, 0);
        }
        {
            float ex[4];
            #pragma unroll
            for (int r = 0; r < 4; r++) ex[r] = (m < 12) ? __expf(S[r] * 0.125f) : 0.f;
            #pragma unroll
            for (int r = 0; r < 4; r++){
                float s = wred16_sum(ex[r]);
                ex[r] = ex[r] / s;
            }
            #pragma unroll
            for (int r = 0; r < 4; r++) Ps[(g << 2) + r][m] = ex[r];
        }
        lds_fence();

        float y[12];
        {
            float xr[12];
            #pragma unroll
            for (int k = 0; k < 12; k++) xr[k] = b2f(xs[GX1(k, lane << 1) >> 1]);
            #pragma unroll
            for (int q = 0; q < 12; q++){
                float4 pa = *(const float4*)&Ps[q][0];
                float4 pb = *(const float4*)&Ps[q][4];
                float4 pc = *(const float4*)&Ps[q][8];
                float c = pa.x*xr[0]+pa.y*xr[1]+pa.z*xr[2]+pa.w*xr[3]
                        + pb.x*xr[4]+pb.y*xr[5]+pb.z*xr[6]+pb.w*xr[7]
                        + pc.x*xr[8]+pc.y*xr[9]+pc.z*xr[10]+pc.w*xr[11];
                y[q] = xr[q] + c;
                xs[GX1(q, lane << 1) >> 1] = f2b(y[q]);
            }
        }
        lds_fence();

        {
            v4f R = {0.f,0.f,0.f,0.f}, Q = {0.f,0.f,0.f,0.f};
            v8s f0 = *(const v8s*)((const char*)xs + GX1(m, (g << 4)));
            v8s f1 = *(const v8s*)((const char*)xs + GX1(m, 64 + (g << 4)));
            R = __builtin_amdgcn_mfma_f32_16x16x32_bf16(f0, ones, R, 0, 0, 0);
            R = __builtin_amdgcn_mfma_f32_16x16x32_bf16(f1, ones, R, 0, 0, 0);
            Q = __builtin_amdgcn_mfma_f32_16x16x32_bf16(f0, f0, Q, 0, 0, 0);
            Q = __builtin_amdgcn_mfma_f32_16x16x32_bf16(f1, f1, Q, 0, 0, 0);
            if (isdiag){ Ps[m][16] = R[dr]; Ps[m][17] = Q[dr]; }
        }
        lds_fence();
        {
            float g1 = b2f(ln1g[layer * 64 + lane]), bb1 = b2f(ln1b[layer * 64 + lane]);
            #pragma unroll
            for (int q = 0; q < 12; q++){
                float2 st = *(const float2*)&Ps[q][16];
                float mu = st.x * 0.015625f;
                float var = st.y * 0.015625f - mu * mu;
                xs[GX1(q, lane << 1) >> 1] = f2b((y[q] - mu) * rsqrtf(var + 1e-5f) * g1 + bb1);
            }
        }
        lds_fence();

        {
            v8s a0 = *(const v8s*)((const char*)xs + GX1(m, (g << 4)));
            v8s a1 = *(const v8s*)((const char*)xs + GX1(m, 64 + (g << 4)));
            const u16* wf1 = w1f + layer * 8192;
            #pragma unroll
            for (int nt = 0; nt < 8; nt++){
                v8s bfa = *(const v8s*)(wf1 + (((nt << 1) + 0) << 9) + (lane << 3));
                v8s bfb = *(const v8s*)(wf1 + (((nt << 1) + 1) << 9) + (lane << 3));
                v4f h = {0.f, 0.f, 0.f, 0.f};
                h = __builtin_amdgcn_mfma_f32_16x16x32_bf16(a0, bfa, h, 0, 0, 0);
                h = __builtin_amdgcn_mfma_f32_16x16x32_bf16(a1, bfb, h, 0, 0, 0);
                float bia = b2f(b1[layer * 128 + (nt << 4) + m]);
                #pragma unroll
                for (int r = 0; r < 4; r++)
                    hs[GH1((g << 2) + r, ((nt << 4) | m) << 1) >> 1] = f2b(fmaxf(h[r] + bia, 0.f));
            }
        }
        lds_fence();

        {
            v8s ha[4];
            #pragma unroll
            for (int c = 0; c < 4; c++)
                ha[c] = *(const v8s*)((const char*)hs + GH1(m, (c << 6) + (g << 4)));
            lds_fence();
            float* os = (float*)hs;
            const u16* wf2 = w2f + layer * 8192;
            #pragma unroll
            for (int nt = 0; nt < 4; nt++){
                v4f o = {0.f, 0.f, 0.f, 0.f};
                #pragma unroll
                for (int c = 0; c < 4; c++){
                    v8s bf = *(const v8s*)(wf2 + ((((nt << 2) + c) << 9) + (lane << 3)));
                    o = __builtin_amdgcn_mfma_f32_16x16x32_bf16(ha[c], bf, o, 0, 0, 0);
                }
                float bo = b2f(b2[layer * 64 + (nt << 4) + m]);
                #pragma unroll
                for (int r = 0; r < 4; r++)
                    os[((g << 2) + r) * 64 + (nt << 4) + m] = o[r] + bo;
            }
        }
        lds_fence();

        {
            const float* os = (const float*)hs;
            #pragma unroll
            for (int q = 0; q < 12; q++){
                y[q] = b2f(xs[GX1(q, lane << 1) >> 1]) + os[q * 64 + lane];
            }
            lds_fence();
            #pragma unroll
            for (int q = 0; q < 12; q++)
                xs[GX1(q, lane << 1) >> 1] = f2b(y[q]);
        }
        lds_fence();
        {
            v4f R = {0.f,0.f,0.f,0.f}, Q = {0.f,0.f,0.f,0.f};
            v8s f0 = *(const v8s*)((const char*)xs + GX1(m, (g << 4)));
            v8s f1 = *(const v8s*)((const char*)xs + GX1(m, 64 + (g << 4)));
            R = __builtin_amdgcn_mfma_f32_16x16x32_bf16(f0, ones, R, 0, 0, 0);
            R = __builtin_amdgcn_mfma_f32_16x16x32_bf16(f1, ones, R, 0, 0, 0);
            Q = __builtin_amdgcn_mfma_f32_16x16x32_bf16(f0, f0, Q, 0, 0, 0);
            Q = __builtin_amdgcn_mfma_f32_16x16x32_bf16(f1, f1, Q, 0, 0, 0);
            if (isdiag){ Ps[m][16] = R[dr]; Ps[m][17] = Q[dr]; }
        }
        lds_fence();
        {
            float g2 = b2f(ln2g[layer * 64 + lane]), bb2 = b2f(ln2b[layer * 64 + lane]);
            #pragma unroll
            for (int q = 0; q < 12; q++){
                float2 st = *(const float2*)&Ps[q][16];
                float mu = st.x * 0.015625f;
                float var = st.y * 0.015625f - mu * mu;
                float xv = (y[q] - mu) * rsqrtf(var + 1e-5f) * g2 + bb2;
                if (layer == 0) xs[GX1(q, lane << 1) >> 1] = f2b(xv);
                else            fsum += xv;
            }
        }
        lds_fence();
    }
    outp[(size_t)seq * 256 + 192 + lane] = f2b(fsum * (1.0f / 12.0f));
}

__global__ __launch_bounds__(256) void embed_src_kernel(
    const int* __restrict__ poi, const float* __restrict__ timev,
    const void* __restrict__ emb_poi, u16* __restrict__ src,
    const int* __restrict__ flag)
{
    const int bl = blockIdx.x;
    const int d  = threadIdx.x;
    const int b  = bl / 100;
    const int isbf = *flag;
    float t0 = timev[b * 100];
    float tN = timev[b * 100 + 99];
    float tv = timev[bl];
    float pos = (tv - t0) / (tN - t0 + 1e-9f) * 99.0f;
    int j = d & 127;
    float dvv = __expf(-(float)j * 0.07195578415606393f);
    float ang = pos * dvv;
    float pe = (d < 128) ? __sinf(ang) : __cosf(ang);
    size_t off = (size_t)bl * 256 + d;
    float val = (d < 192) ? ldm(emb_poi, (size_t)poi[bl] * 192 + d, isbf) : b2f(src[off]);
    src[off] = f2b(val + pe);
}

__global__ __launch_bounds__(256) void embed_tgt_kernel(
    const int* __restrict__ poi, const void* __restrict__ emb_poi,
    u16* __restrict__ tgt, int n, const int* __restrict__ flag)
{
    int i = blockIdx.x * 256 + threadIdx.x;
    if (i >= n * 192) return;
    int bt = i / 192; int d = i - bt * 192;
    tgt[(size_t)bt * 256 + d] = f2b(ldm(emb_poi, (size_t)poi[bt] * 192 + d, *flag));
}

__global__ __launch_bounds__(256) void relmax_kernel(
    const void* __restrict__ tm, const void* __restrict__ gm,
    float* __restrict__ relm, const int* __restrict__ flag)
{
    const int b = blockIdx.x, tid = threadIdx.x;
    const int isbf = *flag;
    size_t base = (size_t)b * 10000;
    float tmax = -1e30f, gmax = -1e30f;
    for (int i = tid; i < 10000; i += 256){
        tmax = fmaxf(tmax, fminf(ldm(tm, base + i, isbf), 0.5f));
        gmax = fmaxf(gmax, fminf(ldm(gm, base + i, isbf), 0.5f));
    }
    tmax = wred_max(tmax); gmax = wred_max(gmax);
    __shared__ float st[4], sg[4];
    if ((tid & 63) == 0){ st[tid >> 6] = tmax; sg[tid >> 6] = gmax; }
    __syncthreads();
    if (tid == 0){
        relm[b * 2]     = fmaxf(fmaxf(st[0], st[1]), fmaxf(st[2], st[3]));
        relm[b * 2 + 1] = fmaxf(fmaxf(sg[0], sg[1]), fmaxf(sg[2], sg[3]));
    }
}

// =======================================================================
// attn (v4): MFMA scores from global Q/K; vector AV; FUSED residual+LN1.
// =======================================================================
__global__ __launch_bounds__(256) void attn_kernel(
    const u16* __restrict__ QB, const u16* __restrict__ Kg, const u16* __restrict__ Vg,
    u16* __restrict__ SRC,
    const void* __restrict__ tmp_, const void* __restrict__ gmp_,
    const float* __restrict__ relm,
    const u16* __restrict__ lng, const u16* __restrict__ lnb,
    const int* __restrict__ flag)
{
    __shared__ __align__(16) u16 KV[100][264];
    __shared__ __align__(16) u16 Amat[50][112];

    const int blk = blockIdx.x;
    const int b = blk >> 1, h = blk & 1;
    const int tid = threadIdx.x;
    const int w = tid >> 6, lane = tid & 63;
    const int l15 = lane & 15, lg = lane >> 4;
    const int q0 = h * 50;
    const int nk = q0 + 50;
    const int isbf = *flag;
    const float tmax = relm[b * 2], gmax = relm[b * 2 + 1];

    const u16* Vb = Vg + (size_t)b * 100 * 256;
    for (int i = tid; i < nk * 128; i += 256){
        int row = i >> 7, c2 = (i & 127) * 2;
        *(ushort2*)&KV[row][c2] = *(const ushort2*)(Vb + row * 256 + c2);
    }

    const int ntc = (h == 0) ? 4 : 7;
    const int qrow = q0 + w * 16 + l15;
    const u16* Aq = QB + ((size_t)b * 100 + (qrow < 100 ? qrow : 99)) * 256 + (lg << 3);
    const u16* Kb = Kg + (size_t)b * 100 * 256;
    v4f S[7];
    #pragma unroll
    for (int nt = 0; nt < 7; nt++) S[nt] = (v4f){0.f, 0.f, 0.f, 0.f};
    const u16* Bp[7];
    for (int nt = 0; nt < ntc; nt++){
        int kt = nt * 16 + l15;
        Bp[nt] = Kb + (size_t)(kt < 100 ? kt : 99) * 256 + (lg << 3);
    }
    for (int c = 0; c < 8; c++){
        v8s af = *(const v8s*)(Aq + (c << 5));
        for (int nt = 0; nt < ntc; nt++){
            v8s bf = *(const v8s*)(Bp[nt] + (c << 5));
            S[nt] = __builtin_amdgcn_mfma_f32_16x16x32_bf16(af, bf, S[nt], 0, 0, 0);
        }
    }

    float P[7][4];
    #pragma unroll
    for (int r = 0; r < 4; r++){
        int qrel = w * 16 + (lg << 2) + r;
        int q = q0 + qrel;
        int qc = q < 100 ? q : 99;
        size_t rbase = ((size_t)b * 100 + qc) * 100;
        float sv[7];
        float mx = -1e30f;
        for (int nt = 0; nt < ntc; nt++){
            int kt = nt * 16 + l15;
            int ktc = kt < 100 ? kt : 99;
            float rel = (tmax - fminf(ldm(tmp_, rbase + ktc, isbf), 0.5f))
                      + (gmax - fminf(ldm(gmp_, rbase + ktc, isbf), 0.5f));
            float s = S[nt][r] * 0.0625f + rel;
            if (kt > q) s = -1e30f;
            sv[nt] = s;
            mx = fmaxf(mx, s);
        }
        mx = wred16_max(mx);
        float sum = 0.f;
        for (int nt = 0; nt < ntc; nt++){ sv[nt] = __expf(sv[nt] - mx); sum += sv[nt]; }
        sum = wred16_sum(sum);
        float inv = 1.0f / sum;
        for (int nt = 0; nt < ntc; nt++) P[nt][r] = sv[nt] * inv;
    }
    #pragma unroll
    for (int r = 0; r < 4; r++){
        int qrel = w * 16 + (lg << 2) + r;
        if (qrel < 50){
            for (int nt = 0; nt < ntc; nt++)
                Amat[qrel][nt * 16 + l15] = f2b(P[nt][r]);
        }
    }
    __syncthreads();

    for (int qq = 0; qq < 13; qq++){
        const int qr = qq * 4 + w;
        const int q  = q0 + qr;
        if (qr < 50){
            float o00 = 0.f, o01 = 0.f, o10 = 0.f, o11 = 0.f;
            const int kfull = (q + 1) & ~7;
            for (int k8 = 0; k8 < (kfull >> 3); k8++){
                uint4 av = *(const uint4*)&Amat[qr][k8 * 8];
                float p[8] = { lo2f(av.x), hi2f(av.x), lo2f(av.y), hi2f(av.y),
                               lo2f(av.z), hi2f(av.z), lo2f(av.w), hi2f(av.w) };
                #pragma unroll
                for (int j = 0; j < 8; j++){
                    int k = k8 * 8 + j;
                    u32 v0 = *(const u32*)&KV[k][2 * lane];
                    u32 v1 = *(const u32*)&KV[k][128 + 2 * lane];
                    o00 += p[j] * lo2f(v0); o01 += p[j] * hi2f(v0);
                    o10 += p[j] * lo2f(v1); o11 += p[j] * hi2f(v1);
                }
            }
            for (int k = kfull; k <= q; k++){
                float a = b2f(Amat[qr][k]);
                u32 v0 = *(const u32*)&KV[k][2 * lane];
                u32 v1 = *(const u32*)&KV[k][128 + 2 * lane];
                o00 += a * lo2f(v0); o01 += a * hi2f(v0);
                o10 += a * lo2f(v1); o11 += a * hi2f(v1);
            }
            u16* Sg = SRC + ((size_t)b * 100 + q) * 256;
            u32 s0v = *(const u32*)&Sg[2 * lane];
            u32 s1v = *(const u32*)&Sg[128 + 2 * lane];
            float y0 = o00 + lo2f(s0v), y1 = o01 + hi2f(s0v);
            float y2 = o10 + lo2f(s1v), y3 = o11 + hi2f(s1v);
            float s1 = y0 + y1 + y2 + y3;
            float s2 = y0*y0 + y1*y1 + y2*y2 + y3*y3;
            s1 = wred_sum(s1); s2 = wred_sum(s2);
            float mu = s1 * (1.0f / 256.0f);
            float var = s2 * (1.0f / 256.0f) - mu * mu;
            float rs = rsqrtf(var + 1e-5f);
            u32 g0 = *(const u32*)&lng[2 * lane], g1 = *(const u32*)&lng[128 + 2 * lane];
            u32 b0 = *(const u32*)&lnb[2 * lane], b1 = *(const u32*)&lnb[128 + 2 * lane];
            ushort2 w0, w1;
            w0.x = f2b((y0 - mu) * rs * lo2f(g0) + lo2f(b0));
            w0.y = f2b((y1 - mu) * rs * hi2f(g0) + hi2f(b0));
            w1.x = f2b((y2 - mu) * rs * lo2f(g1) + lo2f(b1));
            w1.y = f2b((y3 - mu) * rs * hi2f(g1) + hi2f(b1));
            *(ushort2*)&Sg[2 * lane]       = w0;
            *(ushort2*)&Sg[128 + 2 * lane] = w1;
        }
    }
}

__global__ __launch_bounds__(256) void decv_kernel(
    const u16* __restrict__ SRC, const u16* __restrict__ wv, float* __restrict__ VS)
{
    __shared__ float sv[256];
    const int b = blockIdx.x, n = threadIdx.x;
    const u16* s = SRC + ((size_t)b * 100 + 99) * 256;
    sv[n] = b2f(s[n]);
    __syncthreads();
    float acc = 0.f;
    for (int d = 0; d < 256; d++) acc += sv[d] * b2f(wv[d * 256 + n]);
    VS[(size_t)b * 256 + n] = acc;
}

__global__ __launch_bounds__(256) void decfinal_kernel(
    const u16* __restrict__ TGT, const u16* __restrict__ SRC,
    const float* __restrict__ VS,
    const u16* __restrict__ dlg, const u16* __restrict__ dlb,
    const u16* __restrict__ ng,  const u16* __restrict__ nb,
    void* __restrict__ outp, const int* __restrict__ flag)
{
    __shared__ float red2[4][2];
    __shared__ float red1[4];
    const int bt = blockIdx.x, d = threadIdx.x;
    const int b = bt / 101;
    float tg  = b2f(TGT[(size_t)bt * 256 + d]);
    float mem = b2f(SRC[((size_t)b * 100 + 99) * 256 + d]);
    float y = tg + VS[(size_t)b * 256 + d];
    float a = y, bb = y * y;
    block_sum2(a, bb, red2, d);
    float mu1 = a * (1.0f / 256.0f);
    float v1 = bb * (1.0f / 256.0f) - mu1 * mu1;
    float x = (y - mu1) * rsqrtf(v1 + 1e-5f) * b2f(dlg[d]) + b2f(dlb[d]);
    float y2 = x + mem;
    float a2 = y2, b2_ = y2 * y2;
    block_sum2(a2, b2_, red2, d);
    float mu2 = a2 * (1.0f / 256.0f);
    float v2 = b2_ * (1.0f / 256.0f) - mu2 * mu2;
    float o = (y2 - mu2) * rsqrtf(v2 + 1e-5f) * b2f(ng[d]) + b2f(nb[d]);
    float tot = block_sum256(o * tg, red1, d);
    if (d == 0){
        if (*flag) ((u16*)outp)[bt] = f2b(tot);
        else       ((float*)outp)[bt] = tot;
    }
}

extern "C" void kernel_launch(void* const* d_in, const int* in_sizes, int n_in,
                              void* d_out, int out_size, void* d_ws, size_t ws_size,
                              hipStream_t stream)
{
    char* ws = (char*)d_ws;
    size_t off = 0;
    auto AL = [&](size_t bytes){ size_t o = off; off += (bytes + 255) & ~(size_t)255; return o; };
    const size_t FLAGO = AL(4);
    const size_t CTIME = AL(51200 * 4);
    const size_t CEQK  = AL(262144 * 2);
    const size_t CGW1  = AL(16384 * 2), CGB1 = AL(256 * 2), CGW2 = AL(16384 * 2), CGB2 = AL(128 * 2);
    const size_t CGL1G = AL(128 * 2), CGL1B = AL(128 * 2), CGL2G = AL(128 * 2), CGL2B = AL(128 * 2);
    const size_t CEWQ  = AL(131072 * 2), CEWK = AL(131072 * 2), CEWV = AL(131072 * 2);
    const size_t CEW1  = AL(262144 * 2), CEB1 = AL(1024 * 2), CEW2 = AL(262144 * 2), CEB2 = AL(512 * 2);
    const size_t CEL1G = AL(512 * 2), CEL1B = AL(512 * 2), CEL2G = AL(512 * 2), CEL2B = AL(512 * 2);
    const size_t CDWV  = AL(65536 * 2), CDLG = AL(256 * 2), CDLB = AL(256 * 2), CNG = AL(256 * 2), CNB = AL(256 * 2);
    const size_t W1FO  = AL(16384 * 2), W2FO = AL(16384 * 2);
    const size_t QKVFO = AL(786432 * 2);
    const size_t W1FEO = AL(524288 * 2);
    const size_t W2FEO = AL(524288 * 2);
    const size_t RELMO = AL(512 * 2 * 4);
    const size_t VSO   = AL(512 * 256 * 4);
    const size_t SRCO  = AL((size_t)51200 * 256 * 2);
    const size_t TGTO  = AL((size_t)51712 * 256 * 2);
    const size_t B1O   = AL((size_t)51200 * 256 * 2);
    const size_t B2O   = AL((size_t)51200 * 256 * 2);
    const size_t B3O   = AL((size_t)51200 * 256 * 2);
    (void)ws_size; (void)in_sizes; (void)n_in; (void)out_size;

    int*   FLAG = (int*)(ws + FLAGO);
    float* CT   = (float*)(ws + CTIME);
    u16 *cEQK=(u16*)(ws+CEQK), *cGW1=(u16*)(ws+CGW1), *cGB1=(u16*)(ws+CGB1), *cGW2=(u16*)(ws+CGW2),
        *cGB2=(u16*)(ws+CGB2), *cGL1G=(u16*)(ws+CGL1G), *cGL1B=(u16*)(ws+CGL1B), *cGL2G=(u16*)(ws+CGL2G),
        *cGL2B=(u16*)(ws+CGL2B), *cEWQ=(u16*)(ws+CEWQ), *cEWK=(u16*)(ws+CEWK), *cEWV=(u16*)(ws+CEWV),
        *cEW1=(u16*)(ws+CEW1), *cEB1=(u16*)(ws+CEB1), *cEW2=(u16*)(ws+CEW2), *cEB2=(u16*)(ws+CEB2),
        *cEL1G=(u16*)(ws+CEL1G), *cEL1B=(u16*)(ws+CEL1B), *cEL2G=(u16*)(ws+CEL2G), *cEL2B=(u16*)(ws+CEL2B),
        *cDWV=(u16*)(ws+CDWV), *cDLG=(u16*)(ws+CDLG), *cDLB=(u16*)(ws+CDLB), *cNG=(u16*)(ws+CNG),
        *cNB=(u16*)(ws+CNB);
    u16* W1F   = (u16*)(ws + W1FO);
    u16* W2F   = (u16*)(ws + W2FO);
    u16* QKVF  = (u16*)(ws + QKVFO);
    u16* W1FE  = (u16*)(ws + W1FEO);
    u16* W2FE  = (u16*)(ws + W2FEO);
    float* RELM = (float*)(ws + RELMO);
    float* VS   = (float*)(ws + VSO);
    u16* SRC = (u16*)(ws + SRCO);
    u16* TGT = (u16*)(ws + TGTO);
    u16* B1  = (u16*)(ws + B1O);
    u16* B2  = (u16*)(ws + B2O);
    u16* B3  = (u16*)(ws + B3O);
    u16* Hh  = B2;

    const int* src_poi = (const int*)d_in[0];
    const int* src_qk  = (const int*)d_in[1];
    const int* tgt_poi = (const int*)d_in[7];
    const int* tgt_qk  = (const int*)d_in[8];

    probe_kernel<<<1, 64, 0, stream>>>((const u32*)d_in[38], FLAG);

    ConvArgs ca;
    const int srcidx[NSEG] = {13,14,15,16,17,18,19,20,21,22,23,24,25,26,27,28,29,30,31,32,35,36,37,38,39};
    u16* dsts[NSEG] = {cEQK,cGW1,cGB1,cGW2,cGB2,cGL1G,cGL1B,cGL2G,cGL2B,cEWQ,cEWK,cEWV,
                       cEW1,cEB1,cEW2,cEB2,cEL1G,cEL1B,cEL2G,cEL2B,cDWV,cDLG,cDLB,cNG,cNB};
    const int ns[NSEG] = {262144,16384,256,16384,128,128,128,128,128,131072,131072,131072,
                          262144,1024,262144,512,512,512,512,512,65536,256,256,256,256};
    for (int i = 0; i < NSEG; i++){ ca.src[i] = d_in[srcidx[i]]; ca.dst[i] = dsts[i]; ca.n[i] = ns[i]; }
    convert_kernel<<<dim3(1024, NSEG), 256, 0, stream>>>(ca, FLAG);
    convert_time_kernel<<<200, 256, 0, stream>>>(d_in[2], CT, FLAG);

    packfrag_kernel<<<64, 256, 0, stream>>>(cGW1, W1F, 64, 128, 2);
    packfrag_kernel<<<64, 256, 0, stream>>>(cGW2, W2F, 128, 64, 2);
    packfrag3_kernel<<<3072, 256, 0, stream>>>(cEWQ, cEWK, cEWV, QKVF);
    packfrag_kernel<<<1024, 256, 0, stream>>>(cEW1, W1FE, 256, 512, 2);
    packfrag_kernel<<<1024, 256, 0, stream>>>(cEW2, W2FE, 512, 256, 2);

    geo6_kernel<<<102912, 64, 0, stream>>>(src_qk, tgt_qk, cEQK, W1F, cGB1, W2F, cGB2,
                                           cGL1G, cGL1B, cGL2G, cGL2B, SRC, TGT);
    embed_src_kernel<<<51200, 256, 0, stream>>>(src_poi, CT, d_in[12], SRC, FLAG);
    embed_tgt_kernel<<<(51712 * 192 + 255) / 256, 256, 0, stream>>>(tgt_poi, d_in[12], TGT, 51712, FLAG);
    relmax_kernel<<<512, 256, 0, stream>>>(d_in[3], d_in[4], RELM, FLAG);

    for (int i = 0; i < 2; i++){
        gemm2_kernel<0,1><<<dim3(400, 6), 256, 0, stream>>>(SRC, QKVF + (size_t)i * 196608, nullptr,
                                                            B1, B2, B3, 51200, 768, 256);
        attn_kernel<<<1024, 256, 0, stream>>>(B1, B2, B3, SRC, d_in[3], d_in[4], RELM,
                                              cEL1G + i * 256, cEL1B + i * 256, FLAG);
        gemm2_kernel<1,0><<<dim3(400, 4), 256, 0, stream>>>(SRC, W1FE + (size_t)i * 131072, cEB1 + i * 512,
                                                            Hh, nullptr, nullptr, 51200, 512, 256);
        gemm3_kernel<<<800, 256, 0, stream>>>(Hh, W2FE + (size_t)i * 131072, cEB2 + i * 256,
                                              SRC, cEL2G + i * 256, cEL2B + i * 256);
    }

    decv_kernel<<<512, 256, 0, stream>>>(SRC, cDWV, VS);
    decfinal_kernel<<<51712, 256, 0, stream>>>(TGT, SRC, VS, cDLG, cDLB, cNG, cNB, d_out, FLAG);
}

// Round 14
// 1214.719 us; speedup vs baseline: 1.1927x; 1.0481x over previous
//
#include <hip/hip_runtime.h>
#include <hip/hip_bf16.h>
#include <stdint.h>

typedef unsigned short u16;
typedef unsigned int   u32;
typedef __attribute__((ext_vector_type(8))) short v8s;
typedef __attribute__((ext_vector_type(4))) float v4f;

__device__ __forceinline__ float b2f(u16 u){ return __uint_as_float(((u32)u) << 16); }
__device__ __forceinline__ float lo2f(u32 u){ return __uint_as_float(u << 16); }
__device__ __forceinline__ float hi2f(u32 u){ return __uint_as_float(u & 0xffff0000u); }
__device__ __forceinline__ u16 f2b(float f){
    u32 x = __float_as_uint(f);
    u32 r = (x + 0x7fffu + ((x >> 16) & 1u)) >> 16;
    return (u16)r;
}
__device__ __forceinline__ float ldm(const void* p, size_t i, int isbf){
    return isbf ? b2f(((const u16*)p)[i]) : ((const float*)p)[i];
}
__device__ __forceinline__ float wred_sum(float v){
    #pragma unroll
    for (int o = 32; o > 0; o >>= 1) v += __shfl_xor(v, o, 64);
    return v;
}
__device__ __forceinline__ float wred_max(float v){
    #pragma unroll
    for (int o = 32; o > 0; o >>= 1) v = fmaxf(v, __shfl_xor(v, o, 64));
    return v;
}
__device__ __forceinline__ float wred16_sum(float v){
    #pragma unroll
    for (int o = 8; o > 0; o >>= 1) v += __shfl_xor(v, o, 64);
    return v;
}
__device__ __forceinline__ float wred16_max(float v){
    #pragma unroll
    for (int o = 8; o > 0; o >>= 1) v = fmaxf(v, __shfl_xor(v, o, 64));
    return v;
}
__device__ __forceinline__ void lds_fence(){
    asm volatile("s_waitcnt lgkmcnt(0)" ::: "memory");
    __builtin_amdgcn_sched_barrier(0);
}
// XCD-chunked bijective swizzle (total % 8 == 0)
__device__ __forceinline__ int xcd_swz(int bid, int total){
    return (bid & 7) * (total >> 3) + (bid >> 3);
}

__global__ void probe_kernel(const u32* __restrict__ ng, int* __restrict__ flag){
    if (threadIdx.x == 0) *flag = (ng[0] == 0x3F803F80u) ? 1 : 0;
}

#define NSEG 25
struct ConvArgs {
    const void* src[NSEG];
    u16*        dst[NSEG];
    int         n[NSEG];
};
__global__ __launch_bounds__(256) void convert_kernel(ConvArgs a, const int* __restrict__ flag){
    int seg = blockIdx.y;
    int i = blockIdx.x * 256 + threadIdx.x;
    if (i >= a.n[seg]) return;
    int isbf = *flag;
    a.dst[seg][i] = f2b(ldm(a.src[seg], i, isbf));
}
__global__ __launch_bounds__(256) void convert_time_kernel(const void* __restrict__ src,
                                                           float* __restrict__ dst,
                                                           const int* __restrict__ flag){
    int i = blockIdx.x * 256 + threadIdx.x;
    if (i >= 51200) return;
    dst[i] = ldm(src, i, *flag);
}

// pack [nlayer][K][N] bf16 weights into MFMA B-fragment order
__global__ __launch_bounds__(256) void packfrag_kernel(
    const u16* __restrict__ W, u16* __restrict__ out, int K, int N, int nlayer)
{
    int i = blockIdx.x * 256 + threadIdx.x;
    int total = nlayer * K * N;
    if (i >= total) return;
    int j = i & 7, lane = (i >> 3) & 63, fc = i >> 9;
    int CT = K >> 5, NT = N >> 4;
    int c = fc % CT, nt = (fc / CT) % NT, layer = fc / (CT * NT);
    int k = c * 32 + ((lane >> 4) << 3) + j, n = (nt << 4) + (lane & 15);
    out[i] = W[(layer * K + k) * N + n];
}

// pack QKV (3x [2][256][256]) into one fragment buffer as N=768
__global__ __launch_bounds__(256) void packfrag3_kernel(
    const u16* __restrict__ Wq, const u16* __restrict__ Wk, const u16* __restrict__ Wv,
    u16* __restrict__ out)
{
    int i = blockIdx.x * 256 + threadIdx.x;
    if (i >= 786432) return;
    int j = i & 7, lane = (i >> 3) & 63, fc = i >> 9;
    int c = fc & 7, nt = (fc >> 3) % 48, layer = fc / (8 * 48);
    int k = c * 32 + ((lane >> 4) << 3) + j, n = (nt << 4) + (lane & 15);
    const u16* W = (n < 256) ? Wq : (n < 512) ? Wk : Wv;
    out[i] = W[(layer * 256 + k) * 256 + (n & 255)];
}

// =======================================================================
// gemm2: LDS-free MFMA GEMM (+ XCD-chunked swizzle)
// =======================================================================
template<int ACT, int SPLIT>
__global__ __launch_bounds__(256) void gemm2_kernel(
    const u16* __restrict__ A, const u16* __restrict__ Bf,
    const u16* __restrict__ bias,
    u16* __restrict__ C0, u16* __restrict__ C1, u16* __restrict__ C2,
    int M, int N, int K)
{
    const int tid = threadIdx.x, w = tid >> 6, lane = tid & 63;
    const int wm = w >> 1, wn = w & 1;
    const int flat = blockIdx.x + gridDim.x * blockIdx.y;
    const int swz = xcd_swz(flat, gridDim.x * gridDim.y);
    const int mb = swz % gridDim.x, nb = swz / gridDim.x;
    const int m0 = mb * 128 + wm * 64;
    const int n0 = nb * 128 + wn * 64;
    const int CT = K >> 5;
    const int l15 = lane & 15, lg = lane >> 4;

    v4f acc[4][4];
    #pragma unroll
    for (int mt = 0; mt < 4; mt++)
        #pragma unroll
        for (int nt = 0; nt < 4; nt++) acc[mt][nt] = (v4f){0.f, 0.f, 0.f, 0.f};

    const u16* Arow = A + (size_t)(m0 + l15) * K + (lg << 3);
    const u16* Bbase = Bf + (((size_t)(n0 >> 4) * CT) << 9) + (lane << 3);

    for (int c = 0; c < CT; c++){
        v8s bfr[4];
        #pragma unroll
        for (int nt = 0; nt < 4; nt++)
            bfr[nt] = *(const v8s*)(Bbase + (((size_t)(nt * CT + c)) << 9));
        #pragma unroll
        for (int mt = 0; mt < 4; mt++){
            v8s af = *(const v8s*)(Arow + (size_t)(mt << 4) * K + (c << 5));
            #pragma unroll
            for (int nt = 0; nt < 4; nt++)
                acc[mt][nt] = __builtin_amdgcn_mfma_f32_16x16x32_bf16(af, bfr[nt], acc[mt][nt], 0, 0, 0);
        }
    }

    #pragma unroll
    for (int nt = 0; nt < 4; nt++){
        int colbase = n0 + (nt << 4);
        float bv = bias ? b2f(bias[colbase + l15]) : 0.f;
        u16* Cp; int cw;
        if (SPLIT){
            int nbk = colbase >> 8;
            Cp = (nbk == 0) ? C0 : (nbk == 1) ? C1 : C2;
            cw = 256;
            colbase &= 255;
        } else { Cp = C0; cw = N; }
        #pragma unroll
        for (int mt = 0; mt < 4; mt++)
            #pragma unroll
            for (int r = 0; r < 4; r++){
                int row = m0 + (mt << 4) + (lg << 2) + r;
                float v = acc[mt][nt][r] + bv;
                if (ACT) v = fmaxf(v, 0.f);
                Cp[(size_t)row * cw + colbase + l15] = f2b(v);
            }
    }
}

// =======================================================================
// gemm3: FFN2 + residual + LN fused (+ XCD-chunked swizzle)
// =======================================================================
__global__ __launch_bounds__(256) void gemm3_kernel(
    const u16* __restrict__ A, const u16* __restrict__ Bf,
    const u16* __restrict__ bias, u16* __restrict__ SRC,
    const u16* __restrict__ g, const u16* __restrict__ bta)
{
    __shared__ float red[64][4][2];
    const int tid = threadIdx.x, w = tid >> 6, lane = tid & 63;
    const int l15 = lane & 15, lg = lane >> 4;
    const int m0 = xcd_swz(blockIdx.x, gridDim.x) * 64;
    const int n0 = w * 64;
    const int CT = 16;   // K=512

    v4f acc[4][4];
    #pragma unroll
    for (int mt = 0; mt < 4; mt++)
        #pragma unroll
        for (int nt = 0; nt < 4; nt++) acc[mt][nt] = (v4f){0.f, 0.f, 0.f, 0.f};

    const u16* Arow = A + (size_t)(m0 + l15) * 512 + (lg << 3);
    const u16* Bbase = Bf + (((size_t)(n0 >> 4) * CT) << 9) + (lane << 3);

    for (int c = 0; c < CT; c++){
        v8s bfr[4];
        #pragma unroll
        for (int nt = 0; nt < 4; nt++)
            bfr[nt] = *(const v8s*)(Bbase + (((size_t)(nt * CT + c)) << 9));
        #pragma unroll
        for (int mt = 0; mt < 4; mt++){
            v8s af = *(const v8s*)(Arow + (size_t)(mt << 4) * 512 + (c << 5));
            #pragma unroll
            for (int nt = 0; nt < 4; nt++)
                acc[mt][nt] = __builtin_amdgcn_mfma_f32_16x16x32_bf16(af, bfr[nt], acc[mt][nt], 0, 0, 0);
        }
    }

    float bv[4];
    #pragma unroll
    for (int nt = 0; nt < 4; nt++) bv[nt] = b2f(bias[n0 + (nt << 4) + l15]);
    #pragma unroll
    for (int mt = 0; mt < 4; mt++){
        #pragma unroll
        for (int r = 0; r < 4; r++){
            int row = m0 + (mt << 4) + (lg << 2) + r;
            float s1 = 0.f, s2 = 0.f;
            #pragma unroll
            for (int nt = 0; nt < 4; nt++){
                int col = n0 + (nt << 4) + l15;
                float y = acc[mt][nt][r] + bv[nt] + b2f(SRC[(size_t)row * 256 + col]);
                acc[mt][nt][r] = y;
                s1 += y; s2 += y * y;
            }
            s1 = wred16_sum(s1); s2 = wred16_sum(s2);
            if (l15 == 0){
                int rr = (mt << 4) + (lg << 2) + r;
                red[rr][w][0] = s1; red[rr][w][1] = s2;
            }
        }
    }
    __syncthreads();
    float gv[4], bb[4];
    #pragma unroll
    for (int nt = 0; nt < 4; nt++){
        gv[nt] = b2f(g[n0 + (nt << 4) + l15]);
        bb[nt] = b2f(bta[n0 + (nt << 4) + l15]);
    }
    #pragma unroll
    for (int mt = 0; mt < 4; mt++){
        #pragma unroll
        for (int r = 0; r < 4; r++){
            int rr = (mt << 4) + (lg << 2) + r;
            int row = m0 + rr;
            float S1 = red[rr][0][0] + red[rr][1][0] + red[rr][2][0] + red[rr][3][0];
            float S2 = red[rr][0][1] + red[rr][1][1] + red[rr][2][1] + red[rr][3][1];
            float mu = S1 * (1.0f / 256.0f);
            float var = S2 * (1.0f / 256.0f) - mu * mu;
            float rs = rsqrtf(var + 1e-5f);
            #pragma unroll
            for (int nt = 0; nt < 4; nt++){
                int col = n0 + (nt << 4) + l15;
                SRC[(size_t)row * 256 + col] = f2b((acc[mt][nt][r] - mu) * rs * gv[nt] + bb[nt]);
            }
        }
    }
}

// =======================================================================
// geo6: one seq per 64-lane wave; MFMA-based LN stats; merged SRC+TGT.
// =======================================================================
#define GX1(r,b) (((((r) << 7) | (b))) ^ (((r) & 7) << 4))
#define GH1(r,b) (((((r) << 8) | (b))) ^ (((r) & 7) << 4))

__global__ __launch_bounds__(64) void geo6_kernel(
    const int* __restrict__ src_qk, const int* __restrict__ tgt_qk,
    const u16* __restrict__ emb,
    const u16* __restrict__ w1f, const u16* __restrict__ b1,
    const u16* __restrict__ w2f, const u16* __restrict__ b2,
    const u16* __restrict__ ln1g, const u16* __restrict__ ln1b,
    const u16* __restrict__ ln2g, const u16* __restrict__ ln2b,
    u16* __restrict__ SRC, u16* __restrict__ TGT)
{
    __shared__ __align__(16) u16 xs[16 * 64];
    __shared__ __align__(16) u16 hs[16 * 128];
    __shared__ __align__(16) float Ps[16][20];

    int seq = blockIdx.x;
    const int* qk = src_qk;
    u16* outp = SRC;
    if (seq >= 51200){ qk = tgt_qk; outp = TGT; seq -= 51200; }

    const int lane = threadIdx.x;
    const int g = lane >> 4, m = lane & 15;

    v8s ones;
    #pragma unroll
    for (int j = 0; j < 8; j++) ones[j] = (short)0x3F80;

    {
        float dv = __expf(-(float)(lane & 31) * 0.28782313662425572f);
        const bool issin = lane < 32;
        #pragma unroll
        for (int t = 0; t < 12; t++){
            int idx = qk[seq * 12 + t];
            float ang = (float)t * dv;
            float pe = issin ? __sinf(ang) : __cosf(ang);
            xs[GX1(t, lane << 1) >> 1] = f2b(b2f(emb[idx * 64 + lane]) + pe);
        }
        #pragma unroll
        for (int r = 12; r < 16; r++) xs[GX1(r, lane << 1) >> 1] = (u16)0;
    }
    lds_fence();

    float fsum = 0.f;
    const bool isdiag = (g == (m >> 2)) && (m < 12);
    const int dr = m & 3;

    for (int layer = 0; layer < 2; layer++){
        v4f S = {0.f, 0.f, 0.f, 0.f};
        {
            v8s f0 = *(const v8s*)((const char*)xs + GX1(m, (g << 4)));
            v8s f1 = *(const v8s*)((const char*)xs + GX1(m, 64 + (g << 4)));
            S = __builtin_amdgcn_mfma_f32_16x16x32_bf16(f0, f0, S, 0, 0, 0);
            S = __builtin_amdgcn_mfma_f32_16x16x32_bf16(f1, f1, S, 0, 0, 0);
        }
        {
            float ex[4];
            #pragma unroll
            for (int r = 0; r < 4; r++) ex[r] = (m < 12) ? __expf(S[r] * 0.125f) : 0.f;
            #pragma unroll
            for (int r = 0; r < 4; r++){
                float s = wred16_sum(ex[r]);
                ex[r] = ex[r] / s;
            }
            #pragma unroll
            for (int r = 0; r < 4; r++) Ps[(g << 2) + r][m] = ex[r];
        }
        lds_fence();

        float y[12];
        {
            float xr[12];
            #pragma unroll
            for (int k = 0; k < 12; k++) xr[k] = b2f(xs[GX1(k, lane << 1) >> 1]);
            #pragma unroll
            for (int q = 0; q < 12; q++){
                float4 pa = *(const float4*)&Ps[q][0];
                float4 pb = *(const float4*)&Ps[q][4];
                float4 pc = *(const float4*)&Ps[q][8];
                float c = pa.x*xr[0]+pa.y*xr[1]+pa.z*xr[2]+pa.w*xr[3]
                        + pb.x*xr[4]+pb.y*xr[5]+pb.z*xr[6]+pb.w*xr[7]
                        + pc.x*xr[8]+pc.y*xr[9]+pc.z*xr[10]+pc.w*xr[11];
                y[q] = xr[q] + c;
                xs[GX1(q, lane << 1) >> 1] = f2b(y[q]);
            }
        }
        lds_fence();

        {
            v4f R = {0.f,0.f,0.f,0.f}, Q = {0.f,0.f,0.f,0.f};
            v8s f0 = *(const v8s*)((const char*)xs + GX1(m, (g << 4)));
            v8s f1 = *(const v8s*)((const char*)xs + GX1(m, 64 + (g << 4)));
            R = __builtin_amdgcn_mfma_f32_16x16x32_bf16(f0, ones, R, 0, 0, 0);
            R = __builtin_amdgcn_mfma_f32_16x16x32_bf16(f1, ones, R, 0, 0, 0);
            Q = __builtin_amdgcn_mfma_f32_16x16x32_bf16(f0, f0, Q, 0, 0, 0);
            Q = __builtin_amdgcn_mfma_f32_16x16x32_bf16(f1, f1, Q, 0, 0, 0);
            if (isdiag){ Ps[m][16] = R[dr]; Ps[m][17] = Q[dr]; }
        }
        lds_fence();
        {
            float g1 = b2f(ln1g[layer * 64 + lane]), bb1 = b2f(ln1b[layer * 64 + lane]);
            #pragma unroll
            for (int q = 0; q < 12; q++){
                float2 st = *(const float2*)&Ps[q][16];
                float mu = st.x * 0.015625f;
                float var = st.y * 0.015625f - mu * mu;
                xs[GX1(q, lane << 1) >> 1] = f2b((y[q] - mu) * rsqrtf(var + 1e-5f) * g1 + bb1);
            }
        }
        lds_fence();

        {
            v8s a0 = *(const v8s*)((const char*)xs + GX1(m, (g << 4)));
            v8s a1 = *(const v8s*)((const char*)xs + GX1(m, 64 + (g << 4)));
            const u16* wf1 = w1f + layer * 8192;
            #pragma unroll
            for (int nt = 0; nt < 8; nt++){
                v8s bfa = *(const v8s*)(wf1 + (((nt << 1) + 0) << 9) + (lane << 3));
                v8s bfb = *(const v8s*)(wf1 + (((nt << 1) + 1) << 9) + (lane << 3));
                v4f h = {0.f, 0.f, 0.f, 0.f};
                h = __builtin_amdgcn_mfma_f32_16x16x32_bf16(a0, bfa, h, 0, 0, 0);
                h = __builtin_amdgcn_mfma_f32_16x16x32_bf16(a1, bfb, h, 0, 0, 0);
                float bia = b2f(b1[layer * 128 + (nt << 4) + m]);
                #pragma unroll
                for (int r = 0; r < 4; r++)
                    hs[GH1((g << 2) + r, ((nt << 4) | m) << 1) >> 1] = f2b(fmaxf(h[r] + bia, 0.f));
            }
        }
        lds_fence();

        {
            v8s ha[4];
            #pragma unroll
            for (int c = 0; c < 4; c++)
                ha[c] = *(const v8s*)((const char*)hs + GH1(m, (c << 6) + (g << 4)));
            lds_fence();
            float* os = (float*)hs;
            const u16* wf2 = w2f + layer * 8192;
            #pragma unroll
            for (int nt = 0; nt < 4; nt++){
                v4f o = {0.f, 0.f, 0.f, 0.f};
                #pragma unroll
                for (int c = 0; c < 4; c++){
                    v8s bf = *(const v8s*)(wf2 + ((((nt << 2) + c) << 9) + (lane << 3)));
                    o = __builtin_amdgcn_mfma_f32_16x16x32_bf16(ha[c], bf, o, 0, 0, 0);
                }
                float bo = b2f(b2[layer * 64 + (nt << 4) + m]);
                #pragma unroll
                for (int r = 0; r < 4; r++)
                    os[((g << 2) + r) * 64 + (nt << 4) + m] = o[r] + bo;
            }
        }
        lds_fence();

        {
            const float* os = (const float*)hs;
            #pragma unroll
            for (int q = 0; q < 12; q++){
                y[q] = b2f(xs[GX1(q, lane << 1) >> 1]) + os[q * 64 + lane];
            }
            lds_fence();
            #pragma unroll
            for (int q = 0; q < 12; q++)
                xs[GX1(q, lane << 1) >> 1] = f2b(y[q]);
        }
        lds_fence();
        {
            v4f R = {0.f,0.f,0.f,0.f}, Q = {0.f,0.f,0.f,0.f};
            v8s f0 = *(const v8s*)((const char*)xs + GX1(m, (g << 4)));
            v8s f1 = *(const v8s*)((const char*)xs + GX1(m, 64 + (g << 4)));
            R = __builtin_amdgcn_mfma_f32_16x16x32_bf16(f0, ones, R, 0, 0, 0);
            R = __builtin_amdgcn_mfma_f32_16x16x32_bf16(f1, ones, R, 0, 0, 0);
            Q = __builtin_amdgcn_mfma_f32_16x16x32_bf16(f0, f0, Q, 0, 0, 0);
            Q = __builtin_amdgcn_mfma_f32_16x16x32_bf16(f1, f1, Q, 0, 0, 0);
            if (isdiag){ Ps[m][16] = R[dr]; Ps[m][17] = Q[dr]; }
        }
        lds_fence();
        {
            float g2 = b2f(ln2g[layer * 64 + lane]), bb2 = b2f(ln2b[layer * 64 + lane]);
            #pragma unroll
            for (int q = 0; q < 12; q++){
                float2 st = *(const float2*)&Ps[q][16];
                float mu = st.x * 0.015625f;
                float var = st.y * 0.015625f - mu * mu;
                float xv = (y[q] - mu) * rsqrtf(var + 1e-5f) * g2 + bb2;
                if (layer == 0) xs[GX1(q, lane << 1) >> 1] = f2b(xv);
                else            fsum += xv;
            }
        }
        lds_fence();
    }
    outp[(size_t)seq * 256 + 192 + lane] = f2b(fsum * (1.0f / 12.0f));
}

__global__ __launch_bounds__(256) void embed_src_kernel(
    const int* __restrict__ poi, const float* __restrict__ timev,
    const void* __restrict__ emb_poi, u16* __restrict__ src,
    const int* __restrict__ flag)
{
    const int bl = blockIdx.x;
    const int d  = threadIdx.x;
    const int b  = bl / 100;
    const int isbf = *flag;
    float t0 = timev[b * 100];
    float tN = timev[b * 100 + 99];
    float tv = timev[bl];
    float pos = (tv - t0) / (tN - t0 + 1e-9f) * 99.0f;
    int j = d & 127;
    float dvv = __expf(-(float)j * 0.07195578415606393f);
    float ang = pos * dvv;
    float pe = (d < 128) ? __sinf(ang) : __cosf(ang);
    size_t off = (size_t)bl * 256 + d;
    float val = (d < 192) ? ldm(emb_poi, (size_t)poi[bl] * 192 + d, isbf) : b2f(src[off]);
    src[off] = f2b(val + pe);
}

__global__ __launch_bounds__(256) void embed_tgt_kernel(
    const int* __restrict__ poi, const void* __restrict__ emb_poi,
    u16* __restrict__ tgt, int n, const int* __restrict__ flag)
{
    int i = blockIdx.x * 256 + threadIdx.x;
    if (i >= n * 192) return;
    int bt = i / 192; int d = i - bt * 192;
    tgt[(size_t)bt * 256 + d] = f2b(ldm(emb_poi, (size_t)poi[bt] * 192 + d, *flag));
}

__global__ __launch_bounds__(256) void relmax_kernel(
    const void* __restrict__ tm, const void* __restrict__ gm,
    float* __restrict__ relm, const int* __restrict__ flag)
{
    const int b = blockIdx.x, tid = threadIdx.x;
    const int isbf = *flag;
    size_t base = (size_t)b * 10000;
    float tmax = -1e30f, gmax = -1e30f;
    for (int i = tid; i < 10000; i += 256){
        tmax = fmaxf(tmax, fminf(ldm(tm, base + i, isbf), 0.5f));
        gmax = fmaxf(gmax, fminf(ldm(gm, base + i, isbf), 0.5f));
    }
    tmax = wred_max(tmax); gmax = wred_max(gmax);
    __shared__ float st[4], sg[4];
    if ((tid & 63) == 0){ st[tid >> 6] = tmax; sg[tid >> 6] = gmax; }
    __syncthreads();
    if (tid == 0){
        relm[b * 2]     = fmaxf(fmaxf(st[0], st[1]), fmaxf(st[2], st[3]));
        relm[b * 2 + 1] = fmaxf(fmaxf(sg[0], sg[1]), fmaxf(sg[2], sg[3]));
    }
}

// =======================================================================
// attn (v4): MFMA scores from global Q/K; vector AV; fused residual+LN1.
// (+ XCD-chunked swizzle: (b,h) pairs co-locate per XCD)
// =======================================================================
__global__ __launch_bounds__(256) void attn_kernel(
    const u16* __restrict__ QB, const u16* __restrict__ Kg, const u16* __restrict__ Vg,
    u16* __restrict__ SRC,
    const void* __restrict__ tmp_, const void* __restrict__ gmp_,
    const float* __restrict__ relm,
    const u16* __restrict__ lng, const u16* __restrict__ lnb,
    const int* __restrict__ flag)
{
    __shared__ __align__(16) u16 KV[100][264];
    __shared__ __align__(16) u16 Amat[50][112];

    const int blk = xcd_swz(blockIdx.x, gridDim.x);
    const int b = blk >> 1, h = blk & 1;
    const int tid = threadIdx.x;
    const int w = tid >> 6, lane = tid & 63;
    const int l15 = lane & 15, lg = lane >> 4;
    const int q0 = h * 50;
    const int nk = q0 + 50;
    const int isbf = *flag;
    const float tmax = relm[b * 2], gmax = relm[b * 2 + 1];

    const u16* Vb = Vg + (size_t)b * 100 * 256;
    for (int i = tid; i < nk * 128; i += 256){
        int row = i >> 7, c2 = (i & 127) * 2;
        *(ushort2*)&KV[row][c2] = *(const ushort2*)(Vb + row * 256 + c2);
    }

    const int ntc = (h == 0) ? 4 : 7;
    const int qrow = q0 + w * 16 + l15;
    const u16* Aq = QB + ((size_t)b * 100 + (qrow < 100 ? qrow : 99)) * 256 + (lg << 3);
    const u16* Kb = Kg + (size_t)b * 100 * 256;
    v4f S[7];
    #pragma unroll
    for (int nt = 0; nt < 7; nt++) S[nt] = (v4f){0.f, 0.f, 0.f, 0.f};
    const u16* Bp[7];
    for (int nt = 0; nt < ntc; nt++){
        int kt = nt * 16 + l15;
        Bp[nt] = Kb + (size_t)(kt < 100 ? kt : 99) * 256 + (lg << 3);
    }
    for (int c = 0; c < 8; c++){
        v8s af = *(const v8s*)(Aq + (c << 5));
        for (int nt = 0; nt < ntc; nt++){
            v8s bf = *(const v8s*)(Bp[nt] + (c << 5));
            S[nt] = __builtin_amdgcn_mfma_f32_16x16x32_bf16(af, bf, S[nt], 0, 0, 0);
        }
    }

    float P[7][4];
    #pragma unroll
    for (int r = 0; r < 4; r++){
        int qrel = w * 16 + (lg << 2) + r;
        int q = q0 + qrel;
        int qc = q < 100 ? q : 99;
        size_t rbase = ((size_t)b * 100 + qc) * 100;
        float sv[7];
        float mx = -1e30f;
        for (int nt = 0; nt < ntc; nt++){
            int kt = nt * 16 + l15;
            int ktc = kt < 100 ? kt : 99;
            float rel = (tmax - fminf(ldm(tmp_, rbase + ktc, isbf), 0.5f))
                      + (gmax - fminf(ldm(gmp_, rbase + ktc, isbf), 0.5f));
            float s = S[nt][r] * 0.0625f + rel;
            if (kt > q) s = -1e30f;
            sv[nt] = s;
            mx = fmaxf(mx, s);
        }
        mx = wred16_max(mx);
        float sum = 0.f;
        for (int nt = 0; nt < ntc; nt++){ sv[nt] = __expf(sv[nt] - mx); sum += sv[nt]; }
        sum = wred16_sum(sum);
        float inv = 1.0f / sum;
        for (int nt = 0; nt < ntc; nt++) P[nt][r] = sv[nt] * inv;
    }
    #pragma unroll
    for (int r = 0; r < 4; r++){
        int qrel = w * 16 + (lg << 2) + r;
        if (qrel < 50){
            for (int nt = 0; nt < ntc; nt++)
                Amat[qrel][nt * 16 + l15] = f2b(P[nt][r]);
        }
    }
    __syncthreads();

    for (int qq = 0; qq < 13; qq++){
        const int qr = qq * 4 + w;
        const int q  = q0 + qr;
        if (qr < 50){
            float o00 = 0.f, o01 = 0.f, o10 = 0.f, o11 = 0.f;
            const int kfull = (q + 1) & ~7;
            for (int k8 = 0; k8 < (kfull >> 3); k8++){
                uint4 av = *(const uint4*)&Amat[qr][k8 * 8];
                float p[8] = { lo2f(av.x), hi2f(av.x), lo2f(av.y), hi2f(av.y),
                               lo2f(av.z), hi2f(av.z), lo2f(av.w), hi2f(av.w) };
                #pragma unroll
                for (int j = 0; j < 8; j++){
                    int k = k8 * 8 + j;
                    u32 v0 = *(const u32*)&KV[k][2 * lane];
                    u32 v1 = *(const u32*)&KV[k][128 + 2 * lane];
                    o00 += p[j] * lo2f(v0); o01 += p[j] * hi2f(v0);
                    o10 += p[j] * lo2f(v1); o11 += p[j] * hi2f(v1);
                }
            }
            for (int k = kfull; k <= q; k++){
                float a = b2f(Amat[qr][k]);
                u32 v0 = *(const u32*)&KV[k][2 * lane];
                u32 v1 = *(const u32*)&KV[k][128 + 2 * lane];
                o00 += a * lo2f(v0); o01 += a * hi2f(v0);
                o10 += a * lo2f(v1); o11 += a * hi2f(v1);
            }
            u16* Sg = SRC + ((size_t)b * 100 + q) * 256;
            u32 s0v = *(const u32*)&Sg[2 * lane];
            u32 s1v = *(const u32*)&Sg[128 + 2 * lane];
            float y0 = o00 + lo2f(s0v), y1 = o01 + hi2f(s0v);
            float y2 = o10 + lo2f(s1v), y3 = o11 + hi2f(s1v);
            float s1 = y0 + y1 + y2 + y3;
            float s2 = y0*y0 + y1*y1 + y2*y2 + y3*y3;
            s1 = wred_sum(s1); s2 = wred_sum(s2);
            float mu = s1 * (1.0f / 256.0f);
            float var = s2 * (1.0f / 256.0f) - mu * mu;
            float rs = rsqrtf(var + 1e-5f);
            u32 g0 = *(const u32*)&lng[2 * lane], g1 = *(const u32*)&lng[128 + 2 * lane];
            u32 b0 = *(const u32*)&lnb[2 * lane], b1 = *(const u32*)&lnb[128 + 2 * lane];
            ushort2 w0, w1;
            w0.x = f2b((y0 - mu) * rs * lo2f(g0) + lo2f(b0));
            w0.y = f2b((y1 - mu) * rs * hi2f(g0) + hi2f(b0));
            w1.x = f2b((y2 - mu) * rs * lo2f(g1) + lo2f(b1));
            w1.y = f2b((y3 - mu) * rs * hi2f(g1) + hi2f(b1));
            *(ushort2*)&Sg[2 * lane]       = w0;
            *(ushort2*)&Sg[128 + 2 * lane] = w1;
        }
    }
}

__global__ __launch_bounds__(256) void decv_kernel(
    const u16* __restrict__ SRC, const u16* __restrict__ wv, float* __restrict__ VS)
{
    __shared__ float sv[256];
    const int b = blockIdx.x, n = threadIdx.x;
    const u16* s = SRC + ((size_t)b * 100 + 99) * 256;
    sv[n] = b2f(s[n]);
    __syncthreads();
    float acc = 0.f;
    for (int d = 0; d < 256; d++) acc += sv[d] * b2f(wv[d * 256 + n]);
    VS[(size_t)b * 256 + n] = acc;
}

// decfinal2: one 64-lane wave per output row; 4 cols/lane; no LDS/barriers.
__global__ __launch_bounds__(64) void decfinal2_kernel(
    const u16* __restrict__ TGT, const u16* __restrict__ SRC,
    const float* __restrict__ VS,
    const u16* __restrict__ dlg, const u16* __restrict__ dlb,
    const u16* __restrict__ ng,  const u16* __restrict__ nb,
    void* __restrict__ outp, const int* __restrict__ flag)
{
    const int bt = blockIdx.x, lane = threadIdx.x;
    const int b = bt / 101;
    const int c4 = lane * 4;
    ushort4 tg4  = *(const ushort4*)(TGT + (size_t)bt * 256 + c4);
    ushort4 mem4 = *(const ushort4*)(SRC + ((size_t)b * 100 + 99) * 256 + c4);
    float4  vs4  = *(const float4*)(VS + (size_t)b * 256 + c4);
    float tg[4]  = { b2f(tg4.x), b2f(tg4.y), b2f(tg4.z), b2f(tg4.w) };
    float mem[4] = { b2f(mem4.x), b2f(mem4.y), b2f(mem4.z), b2f(mem4.w) };
    float vsv[4] = { vs4.x, vs4.y, vs4.z, vs4.w };
    float y[4], s1 = 0.f, s2 = 0.f;
    #pragma unroll
    for (int i = 0; i < 4; i++){ y[i] = tg[i] + vsv[i]; s1 += y[i]; s2 += y[i]*y[i]; }
    s1 = wred_sum(s1); s2 = wred_sum(s2);
    float mu1 = s1 * (1.0f / 256.0f);
    float v1 = s2 * (1.0f / 256.0f) - mu1 * mu1;
    float rs1 = rsqrtf(v1 + 1e-5f);
    ushort4 dg4 = *(const ushort4*)(dlg + c4), db4 = *(const ushort4*)(dlb + c4);
    float dg[4] = { b2f(dg4.x), b2f(dg4.y), b2f(dg4.z), b2f(dg4.w) };
    float db[4] = { b2f(db4.x), b2f(db4.y), b2f(db4.z), b2f(db4.w) };
    float y2[4], a2 = 0.f, b2s = 0.f;
    #pragma unroll
    for (int i = 0; i < 4; i++){
        float x = (y[i] - mu1) * rs1 * dg[i] + db[i];
        y2[i] = x + mem[i];
        a2 += y2[i]; b2s += y2[i]*y2[i];
    }
    a2 = wred_sum(a2); b2s = wred_sum(b2s);
    float mu2 = a2 * (1.0f / 256.0f);
    float v2 = b2s * (1.0f / 256.0f) - mu2 * mu2;
    float rs2 = rsqrtf(v2 + 1e-5f);
    ushort4 ng4 = *(const ushort4*)(ng + c4), nb4 = *(const ushort4*)(nb + c4);
    float ngv[4] = { b2f(ng4.x), b2f(ng4.y), b2f(ng4.z), b2f(ng4.w) };
    float nbv[4] = { b2f(nb4.x), b2f(nb4.y), b2f(nb4.z), b2f(nb4.w) };
    float tot = 0.f;
    #pragma unroll
    for (int i = 0; i < 4; i++){
        float o = (y2[i] - mu2) * rs2 * ngv[i] + nbv[i];
        tot += o * tg[i];
    }
    tot = wred_sum(tot);
    if (lane == 0){
        if (*flag) ((u16*)outp)[bt] = f2b(tot);
        else       ((float*)outp)[bt] = tot;
    }
}

extern "C" void kernel_launch(void* const* d_in, const int* in_sizes, int n_in,
                              void* d_out, int out_size, void* d_ws, size_t ws_size,
                              hipStream_t stream)
{
    char* ws = (char*)d_ws;
    size_t off = 0;
    auto AL = [&](size_t bytes){ size_t o = off; off += (bytes + 255) & ~(size_t)255; return o; };
    const size_t FLAGO = AL(4);
    const size_t CTIME = AL(51200 * 4);
    const size_t CEQK  = AL(262144 * 2);
    const size_t CGW1  = AL(16384 * 2), CGB1 = AL(256 * 2), CGW2 = AL(16384 * 2), CGB2 = AL(128 * 2);
    const size_t CGL1G = AL(128 * 2), CGL1B = AL(128 * 2), CGL2G = AL(128 * 2), CGL2B = AL(128 * 2);
    const size_t CEWQ  = AL(131072 * 2), CEWK = AL(131072 * 2), CEWV = AL(131072 * 2);
    const size_t CEW1  = AL(262144 * 2), CEB1 = AL(1024 * 2), CEW2 = AL(262144 * 2), CEB2 = AL(512 * 2);
    const size_t CEL1G = AL(512 * 2), CEL1B = AL(512 * 2), CEL2G = AL(512 * 2), CEL2B = AL(512 * 2);
    const size_t CDWV  = AL(65536 * 2), CDLG = AL(256 * 2), CDLB = AL(256 * 2), CNG = AL(256 * 2), CNB = AL(256 * 2);
    const size_t W1FO  = AL(16384 * 2), W2FO = AL(16384 * 2);
    const size_t QKVFO = AL(786432 * 2);
    const size_t W1FEO = AL(524288 * 2);
    const size_t W2FEO = AL(524288 * 2);
    const size_t RELMO = AL(512 * 2 * 4);
    const size_t VSO   = AL(512 * 256 * 4);
    const size_t SRCO  = AL((size_t)51200 * 256 * 2);
    const size_t TGTO  = AL((size_t)51712 * 256 * 2);
    const size_t B1O   = AL((size_t)51200 * 256 * 2);
    const size_t B2O   = AL((size_t)51200 * 256 * 2);
    const size_t B3O   = AL((size_t)51200 * 256 * 2);
    (void)ws_size; (void)in_sizes; (void)n_in; (void)out_size;

    int*   FLAG = (int*)(ws + FLAGO);
    float* CT   = (float*)(ws + CTIME);
    u16 *cEQK=(u16*)(ws+CEQK), *cGW1=(u16*)(ws+CGW1), *cGB1=(u16*)(ws+CGB1), *cGW2=(u16*)(ws+CGW2),
        *cGB2=(u16*)(ws+CGB2), *cGL1G=(u16*)(ws+CGL1G), *cGL1B=(u16*)(ws+CGL1B), *cGL2G=(u16*)(ws+CGL2G),
        *cGL2B=(u16*)(ws+CGL2B), *cEWQ=(u16*)(ws+CEWQ), *cEWK=(u16*)(ws+CEWK), *cEWV=(u16*)(ws+CEWV),
        *cEW1=(u16*)(ws+CEW1), *cEB1=(u16*)(ws+CEB1), *cEW2=(u16*)(ws+CEW2), *cEB2=(u16*)(ws+CEB2),
        *cEL1G=(u16*)(ws+CEL1G), *cEL1B=(u16*)(ws+CEL1B), *cEL2G=(u16*)(ws+CEL2G), *cEL2B=(u16*)(ws+CEL2B),
        *cDWV=(u16*)(ws+CDWV), *cDLG=(u16*)(ws+CDLG), *cDLB=(u16*)(ws+CDLB), *cNG=(u16*)(ws+CNG),
        *cNB=(u16*)(ws+CNB);
    u16* W1F   = (u16*)(ws + W1FO);
    u16* W2F   = (u16*)(ws + W2FO);
    u16* QKVF  = (u16*)(ws + QKVFO);
    u16* W1FE  = (u16*)(ws + W1FEO);
    u16* W2FE  = (u16*)(ws + W2FEO);
    float* RELM = (float*)(ws + RELMO);
    float* VS   = (float*)(ws + VSO);
    u16* SRC = (u16*)(ws + SRCO);
    u16* TGT = (u16*)(ws + TGTO);
    u16* B1  = (u16*)(ws + B1O);
    u16* B2  = (u16*)(ws + B2O);
    u16* B3  = (u16*)(ws + B3O);
    u16* Hh  = B2;

    const int* src_poi = (const int*)d_in[0];
    const int* src_qk  = (const int*)d_in[1];
    const int* tgt_poi = (const int*)d_in[7];
    const int* tgt_qk  = (const int*)d_in[8];

    probe_kernel<<<1, 64, 0, stream>>>((const u32*)d_in[38], FLAG);

    ConvArgs ca;
    const int srcidx[NSEG] = {13,14,15,16,17,18,19,20,21,22,23,24,25,26,27,28,29,30,31,32,35,36,37,38,39};
    u16* dsts[NSEG] = {cEQK,cGW1,cGB1,cGW2,cGB2,cGL1G,cGL1B,cGL2G,cGL2B,cEWQ,cEWK,cEWV,
                       cEW1,cEB1,cEW2,cEB2,cEL1G,cEL1B,cEL2G,cEL2B,cDWV,cDLG,cDLB,cNG,cNB};
    const int ns[NSEG] = {262144,16384,256,16384,128,128,128,128,128,131072,131072,131072,
                          262144,1024,262144,512,512,512,512,512,65536,256,256,256,256};
    for (int i = 0; i < NSEG; i++){ ca.src[i] = d_in[srcidx[i]]; ca.dst[i] = dsts[i]; ca.n[i] = ns[i]; }
    convert_kernel<<<dim3(1024, NSEG), 256, 0, stream>>>(ca, FLAG);
    convert_time_kernel<<<200, 256, 0, stream>>>(d_in[2], CT, FLAG);

    packfrag_kernel<<<64, 256, 0, stream>>>(cGW1, W1F, 64, 128, 2);
    packfrag_kernel<<<64, 256, 0, stream>>>(cGW2, W2F, 128, 64, 2);
    packfrag3_kernel<<<3072, 256, 0, stream>>>(cEWQ, cEWK, cEWV, QKVF);
    packfrag_kernel<<<1024, 256, 0, stream>>>(cEW1, W1FE, 256, 512, 2);
    packfrag_kernel<<<1024, 256, 0, stream>>>(cEW2, W2FE, 512, 256, 2);

    geo6_kernel<<<102912, 64, 0, stream>>>(src_qk, tgt_qk, cEQK, W1F, cGB1, W2F, cGB2,
                                           cGL1G, cGL1B, cGL2G, cGL2B, SRC, TGT);
    embed_src_kernel<<<51200, 256, 0, stream>>>(src_poi, CT, d_in[12], SRC, FLAG);
    embed_tgt_kernel<<<(51712 * 192 + 255) / 256, 256, 0, stream>>>(tgt_poi, d_in[12], TGT, 51712, FLAG);
    relmax_kernel<<<512, 256, 0, stream>>>(d_in[3], d_in[4], RELM, FLAG);

    for (int i = 0; i < 2; i++){
        gemm2_kernel<0,1><<<dim3(400, 6), 256, 0, stream>>>(SRC, QKVF + (size_t)i * 196608, nullptr,
                                                            B1, B2, B3, 51200, 768, 256);
        attn_kernel<<<1024, 256, 0, stream>>>(B1, B2, B3, SRC, d_in[3], d_in[4], RELM,
                                              cEL1G + i * 256, cEL1B + i * 256, FLAG);
        gemm2_kernel<1,0><<<dim3(400, 4), 256, 0, stream>>>(SRC, W1FE + (size_t)i * 131072, cEB1 + i * 512,
                                                            Hh, nullptr, nullptr, 51200, 512, 256);
        gemm3_kernel<<<800, 256, 0, stream>>>(Hh, W2FE + (size_t)i * 131072, cEB2 + i * 256,
                                              SRC, cEL2G + i * 256, cEL2B + i * 256);
    }

    decv_kernel<<<512, 256, 0, stream>>>(SRC, cDWV, VS);
    decfinal2_kernel<<<51712, 64, 0, stream>>>(TGT, SRC, VS, cDLG, cDLB, cNG, cNB, d_out, FLAG);
}